// Round 2
// baseline (1239.729 us; speedup 1.0000x reference)
//
#include <hip/hip_runtime.h>
#include <hip/hip_bf16.h>
#include <stdint.h>

#define HH 101
#define WW 31
#define NN 3131
#define NPAD 3136
#define BB 32
#define NH 8
#define CDIM 256
#define GG 64
#define HP 103
#define WP 33

typedef __attribute__((ext_vector_type(8))) short bf16x8;
typedef __attribute__((ext_vector_type(4))) float f32x4;
typedef __attribute__((ext_vector_type(4))) unsigned short ushort4_t;
typedef __attribute__((ext_vector_type(8))) unsigned short ushort8_t;
typedef __attribute__((ext_vector_type(4))) float float4_t;

static __device__ __forceinline__ unsigned short f2bf(float f) {
  union { float f; uint32_t u; } v; v.f = f;
  uint32_t u = v.u;
  return (unsigned short)((u + 0x7fffu + ((u >> 16) & 1u)) >> 16);
}
static __device__ __forceinline__ float bf2f(unsigned short h) {
  union { uint32_t u; float f; } v; v.u = ((uint32_t)h) << 16;
  return v.f;
}
static __device__ __forceinline__ void gload_lds16(const void* g, void* l) {
  __builtin_amdgcn_global_load_lds((const __attribute__((address_space(1))) void*)g,
                                   (__attribute__((address_space(3))) void*)l, 16, 0, 0);
}

// ---------------- K0: pad + cast x -> bf16 (CB, HP, WP, C), batch offset b0 ----------------
__global__ void k_pad(const float* __restrict__ x, unsigned short* __restrict__ xpad,
                      int b0, int CB) {
  int64_t e = (int64_t)blockIdx.x * blockDim.x + threadIdx.x; // quad index
  const int64_t total = (int64_t)CB * HP * WP * (CDIM / 4);
  if (e >= total) return;
  int c4 = (int)(e % (CDIM / 4));
  int64_t rest = e / (CDIM / 4);
  int xx = (int)(rest % WP); rest /= WP;
  int yy = (int)(rest % HP);
  int b = (int)(rest / HP);
  ushort4_t o;
  if (yy >= 1 && yy <= HH && xx >= 1 && xx <= WW) {
    int n = (yy - 1) * WW + (xx - 1);
    const float4_t v = *(const float4_t*)(x + (((int64_t)(b0 + b) * NN + n) * CDIM + c4 * 4));
    o.x = f2bf(v.x); o.y = f2bf(v.y); o.z = f2bf(v.z); o.w = f2bf(v.w);
  } else {
    o.x = 0; o.y = 0; o.z = 0; o.w = 0;
  }
  *(ushort4_t*)(xpad + e * 4) = o;
}

// ---------------- K1: pack conv weights Wb[t][co(1024)][cin] bf16, bias, gate_w bf16 --------
__global__ void k_wpack(const float* __restrict__ fxw, const float* __restrict__ xw,
                        const float* __restrict__ fxb, const float* __restrict__ xb,
                        const float* __restrict__ gw,
                        unsigned short* __restrict__ Wb, float* __restrict__ bias,
                        unsigned short* __restrict__ gwb) {
  int tid = blockIdx.x * blockDim.x + threadIdx.x;
  const int total = 9 * 1024 * 256;
  if (tid < total) {
    int cin = tid & 255; int rest = tid >> 8; int co = rest & 1023; int t = rest >> 10;
    float v = (co < 512) ? fxw[(int64_t)co * 2304 + cin * 9 + t]
                         : xw[(int64_t)(co - 512) * 2304 + cin * 9 + t];
    Wb[tid] = f2bf(v);
  }
  if (tid < 1024) bias[tid] = (tid < 512) ? fxb[tid] : xb[tid - 512];
  if (tid < 4096) gwb[tid] = f2bf(gw[tid]);
}

// ---------------- K1b: P[h][i][co] = sum_o mlp_w[i][o] * out_w[co][h*64+o] (bf16) ----------
__global__ void k_pprep(const float* __restrict__ mlp, const float* __restrict__ outw,
                        unsigned short* __restrict__ P) {
  int h = blockIdx.x >> 6, i = blockIdx.x & 63, co = threadIdx.x;
  float a = 0.f;
  for (int c = 0; c < 64; ++c) a += mlp[i * 64 + c] * outw[(int64_t)co * 512 + h * 64 + c];
  P[((int64_t)h * 64 + i) * 256 + co] = f2bf(a);
}

// ---------------- K1c: zero pad tails of fxT (cols) and xmid (rows), per chunk ----------
__global__ void k_padzero(unsigned short* __restrict__ fxT, unsigned short* __restrict__ xmid,
                          int CB) {
  int tid = blockIdx.x * blockDim.x + threadIdx.x;
  if (tid >= CB * 2560) return;
  {
    int j = tid % 5; int rc = tid / 5; // rc < CB*512 = (b*8+h)*64+c
    fxT[(int64_t)rc * NPAD + NN + j] = 0;
  }
  {
    int d = tid & 63; int rest = tid >> 6; // rest < CB*40
    int j = rest % 5; int bh = rest / 5;   // bh < CB*8
    xmid[((int64_t)bh * NPAD + NN + j) * 64 + d] = 0;
  }
}

// ---------------- K2: fused implicit-GEMM conv (both convs, N=1024) ----------------
__launch_bounds__(256)
__global__ void k_conv(const unsigned short* __restrict__ xpad,
                       const unsigned short* __restrict__ Wb,
                       const float* __restrict__ bias,
                       unsigned short* __restrict__ fxT,
                       unsigned short* __restrict__ xmid) {
  const int bx = blockIdx.x, mt = blockIdx.y, b = blockIdx.z;
  const int tid = threadIdx.x;
  const int w = tid >> 6, lane = tid & 63;
  __shared__ unsigned short Als[128 * 32];
  __shared__ unsigned short Bls[128 * 32];

  const int chunk = lane & 3;
  const int r1 = w * 16 + (lane >> 2);
  const int r2 = 64 + r1;
  int n1 = mt * 128 + r1; if (n1 >= NN) n1 = NN - 1;
  int n2 = mt * 128 + r2; if (n2 >= NN) n2 = NN - 1;
  const int y1 = n1 / WW, x1 = n1 % WW;
  const int y2 = n2 / WW, x2 = n2 % WW;
  const unsigned short* aB1 = xpad + ((int64_t)(b * HP + y1) * WP + x1) * CDIM + chunk * 8;
  const unsigned short* aB2 = xpad + ((int64_t)(b * HP + y2) * WP + x2) * CDIM + chunk * 8;
  const int co0 = bx * 128;
  const unsigned short* bB1 = Wb + (int64_t)(co0 + r1) * CDIM + chunk * 8;
  const unsigned short* bB2 = Wb + (int64_t)(co0 + r2) * CDIM + chunk * 8;

  const int wm = w >> 1, wn = w & 1;
  const int arow = lane & 15;
  const int koff = (lane >> 4) * 8;

  f32x4 acc[4][4] = {};

  for (int ks = 0; ks < 72; ++ks) {
    const int t = ks >> 3;
    const int cin0 = (ks & 7) << 5;
    const int dy = t / 3, dx = t % 3;
    const int aoff = (dy * WP + dx) * CDIM + cin0;
    const int boff = t * 1024 * CDIM + cin0;
    __syncthreads();
    gload_lds16(aB1 + aoff, &Als[w * 512]);
    gload_lds16(aB2 + aoff, &Als[(4 + w) * 512]);
    gload_lds16(bB1 + boff, &Bls[w * 512]);
    gload_lds16(bB2 + boff, &Bls[(4 + w) * 512]);
    __syncthreads();
    bf16x8 av[4], bv[4];
    #pragma unroll
    for (int mg = 0; mg < 4; ++mg)
      av[mg] = *(const bf16x8*)&Als[(wm * 64 + mg * 16 + arow) * 32 + koff];
    #pragma unroll
    for (int ng = 0; ng < 4; ++ng)
      bv[ng] = *(const bf16x8*)&Bls[(wn * 64 + ng * 16 + arow) * 32 + koff];
    #pragma unroll
    for (int mg = 0; mg < 4; ++mg)
      #pragma unroll
      for (int ng = 0; ng < 4; ++ng)
        acc[mg][ng] = __builtin_amdgcn_mfma_f32_16x16x32_bf16(av[mg], bv[ng], acc[mg][ng], 0, 0, 0);
  }

  #pragma unroll
  for (int mg = 0; mg < 4; ++mg) {
    const int nr = mt * 128 + wm * 64 + mg * 16 + ((lane >> 4) << 2);
    #pragma unroll
    for (int ng = 0; ng < 4; ++ng) {
      const int co = co0 + wn * 64 + ng * 16 + arow;
      const float bvs = bias[co];
      const float v0 = acc[mg][ng][0] + bvs;
      const float v1 = acc[mg][ng][1] + bvs;
      const float v2 = acc[mg][ng][2] + bvs;
      const float v3 = acc[mg][ng][3] + bvs;
      if (co < 512) {
        const int h = co >> 6, c = co & 63;
        unsigned short* dst = fxT + ((int64_t)((b * NH + h) * 64 + c)) * NPAD + nr;
        if (nr + 3 < NN) {
          ushort4_t o; o.x = f2bf(v0); o.y = f2bf(v1); o.z = f2bf(v2); o.w = f2bf(v3);
          *(ushort4_t*)dst = o;
        } else {
          if (nr + 0 < NN) dst[0] = f2bf(v0);
          if (nr + 1 < NN) dst[1] = f2bf(v1);
          if (nr + 2 < NN) dst[2] = f2bf(v2);
          if (nr + 3 < NN) dst[3] = f2bf(v3);
        }
      } else {
        const int h = (co >> 6) & 7, d = co & 63;
        unsigned short* dst = xmid + ((int64_t)(b * NH + h) * NPAD + nr) * 64 + d;
        if (nr + 0 < NN) dst[0] = f2bf(v0);
        if (nr + 1 < NN) dst[64] = f2bf(v1);
        if (nr + 2 < NN) dst[128] = f2bf(v2);
        if (nr + 3 < NN) dst[192] = f2bf(v3);
      }
    }
  }
}

// ---------------- K3: logits MFMA + softmax + eigens (both layouts) ----------------
__global__ void k_eig(const unsigned short* __restrict__ xmid,
                      const unsigned short* __restrict__ gwb,
                      const float* __restrict__ gateb,
                      const float* __restrict__ temperature,
                      const float* __restrict__ inver,
                      unsigned short* __restrict__ eigT,
                      unsigned short* __restrict__ eigN) {
  const int nt = blockIdx.x, h = blockIdx.y, b = blockIdx.z;
  const int w = threadIdx.x >> 6, lane = threadIdx.x & 63;
  const int n0 = nt * 64 + w * 16;
  const int bh = b * NH + h;
  float tv = temperature[h];
  tv = fminf(fmaxf(tv, 0.1f), 5.0f);
  const float itemp = 1.0f / tv;
  const int arow = lane & 15;
  const int koff = (lane >> 4) * 8;
  const unsigned short* aptr = xmid + ((int64_t)bh * NPAD + (n0 + arow)) * 64 + koff;
  bf16x8 a0 = *(const bf16x8*)(aptr);
  bf16x8 a1 = *(const bf16x8*)(aptr + 32);
  f32x4 acc[4] = {};
  #pragma unroll
  for (int ng = 0; ng < 4; ++ng) {
    const unsigned short* bptr = gwb + (ng * 16 + arow) * 64 + koff;
    bf16x8 b0 = *(const bf16x8*)(bptr);
    bf16x8 b1 = *(const bf16x8*)(bptr + 32);
    acc[ng] = __builtin_amdgcn_mfma_f32_16x16x32_bf16(a0, b0, acc[ng], 0, 0, 0);
    acc[ng] = __builtin_amdgcn_mfma_f32_16x16x32_bf16(a1, b1, acc[ng], 0, 0, 0);
  }
  unsigned short evT[4][4]; // [ng][r]
  #pragma unroll
  for (int r = 0; r < 4; ++r) {
    const int n = n0 + ((lane >> 4) << 2) + r;
    float vals[4];
    #pragma unroll
    for (int ng = 0; ng < 4; ++ng) vals[ng] = (acc[ng][r] + gateb[ng * 16 + arow]) * itemp;
    float mx = fmaxf(fmaxf(vals[0], vals[1]), fmaxf(vals[2], vals[3]));
    #pragma unroll
    for (int s = 1; s < 16; s <<= 1) mx = fmaxf(mx, __shfl_xor(mx, s));
    float ex[4]; float sum = 0.f;
    #pragma unroll
    for (int ng = 0; ng < 4; ++ng) { ex[ng] = __expf(vals[ng] - mx); sum += ex[ng]; }
    #pragma unroll
    for (int s = 1; s < 16; s <<= 1) sum += __shfl_xor(sum, s);
    const float inv = 1.0f / sum;
    const bool valid = (n < NN);
    #pragma unroll
    for (int ng = 0; ng < 4; ++ng) {
      const int g = ng * 16 + arow;
      float iv = valid ? inver[(int64_t)n * GG + g] : 0.f;
      unsigned short u = valid ? f2bf(ex[ng] * inv * iv) : (unsigned short)0;
      evT[ng][r] = u;
      eigN[((int64_t)bh * NPAD + n) * 64 + g] = u;
    }
  }
  #pragma unroll
  for (int ng = 0; ng < 4; ++ng) {
    const int g = ng * 16 + arow;
    ushort4_t o; o.x = evT[ng][0]; o.y = evT[ng][1]; o.z = evT[ng][2]; o.w = evT[ng][3];
    *(ushort4_t*)(eigT + ((int64_t)(bh * 64 + g)) * NPAD + n0 + ((lane >> 4) << 2)) = o;
  }
}

// ---------------- K4a: spec partials: spec[g,c] = sum_n eigT[g,n]*fxT[c,n] ----------------
__global__ void k_spec(const unsigned short* __restrict__ eigT,
                       const unsigned short* __restrict__ fxT,
                       float* __restrict__ part) {
  const int half = blockIdx.x, h = blockIdx.y, b = blockIdx.z;
  const int w = threadIdx.x >> 6, lane = threadIdx.x & 63;
  const int s = half * 4 + w;
  const int bh = b * NH + h;
  const int ks0 = (98 * s) >> 3, ks1 = (98 * (s + 1)) >> 3;
  const int arow = lane & 15, koff = (lane >> 4) * 8;
  const unsigned short* eb = eigT + (int64_t)bh * 64 * NPAD;
  const unsigned short* fb = fxT + (int64_t)bh * 64 * NPAD;
  f32x4 acc[4][4] = {};
  for (int ks = ks0; ks < ks1; ++ks) {
    const int k0 = ks * 32 + koff;
    bf16x8 av[4], bv[4];
    #pragma unroll
    for (int mg = 0; mg < 4; ++mg) av[mg] = *(const bf16x8*)(eb + (int64_t)(mg * 16 + arow) * NPAD + k0);
    #pragma unroll
    for (int ng = 0; ng < 4; ++ng) bv[ng] = *(const bf16x8*)(fb + (int64_t)(ng * 16 + arow) * NPAD + k0);
    #pragma unroll
    for (int mg = 0; mg < 4; ++mg)
      #pragma unroll
      for (int ng = 0; ng < 4; ++ng)
        acc[mg][ng] = __builtin_amdgcn_mfma_f32_16x16x32_bf16(av[mg], bv[ng], acc[mg][ng], 0, 0, 0);
  }
  float* pb = part + ((int64_t)bh * 8 + s) * 4096;
  #pragma unroll
  for (int mg = 0; mg < 4; ++mg)
    #pragma unroll
    for (int ng = 0; ng < 4; ++ng)
      #pragma unroll
      for (int r = 0; r < 4; ++r)
        pb[(mg * 16 + ((lane >> 4) << 2) + r) * 64 + ng * 16 + arow] = acc[mg][ng][r];
}

// ---------------- K4b: sum partials, LayerNorm, M2T = (LN(spec) @ P_h)^T bf16 ------------
__global__ void k_ln(const float* __restrict__ part,
                     const float* __restrict__ gamma, const float* __restrict__ beta,
                     const unsigned short* __restrict__ P,
                     unsigned short* __restrict__ m2t) {
  __shared__ float spec[4096];
  __shared__ float red[8];
  __shared__ unsigned short Pl[64 * 256];
  const int bh = blockIdx.x, tid = threadIdx.x;
  const int h = bh & 7;
  const float* pb = part + (int64_t)bh * 8 * 4096;
  float lsum = 0.f, lsq = 0.f;
  for (int e = tid; e < 4096; e += 256) {
    float v = 0.f;
    #pragma unroll
    for (int s = 0; s < 8; ++s) v += pb[s * 4096 + e];
    spec[e] = v; lsum += v; lsq += v * v;
  }
  for (int e = tid; e < 64 * 256; e += 256) Pl[e] = P[(int64_t)h * 64 * 256 + e];
  #pragma unroll
  for (int s = 1; s < 64; s <<= 1) { lsum += __shfl_xor(lsum, s); lsq += __shfl_xor(lsq, s); }
  const int w = tid >> 6, lane = tid & 63;
  if (lane == 0) { red[w] = lsum; red[4 + w] = lsq; }
  __syncthreads();
  const float tsum = red[0] + red[1] + red[2] + red[3];
  const float tsq = red[4] + red[5] + red[6] + red[7];
  const float mu = tsum * (1.0f / 4096.0f);
  const float var = tsq * (1.0f / 4096.0f) - mu * mu;
  const float rs = rsqrtf(var + 1e-5f);
  for (int e = tid; e < 4096; e += 256) {
    spec[e] = (spec[e] - mu) * rs * gamma[e] + beta[e];
  }
  __syncthreads();
  const int co = tid;
  const int b_ = bh >> 3;
  unsigned short* dst = m2t + ((int64_t)(b_ * 256 + co)) * 512 + h * 64;
  float pr[64];
  #pragma unroll
  for (int i = 0; i < 64; ++i) pr[i] = bf2f(Pl[i * 256 + co]);
  for (int g0 = 0; g0 < 64; g0 += 8) {
    ushort8_t o;
    #pragma unroll
    for (int gi = 0; gi < 8; ++gi) {
      float a = 0.f;
      #pragma unroll
      for (int i = 0; i < 64; ++i) a += spec[(g0 + gi) * 64 + i] * pr[i];
      o[gi] = f2bf(a);
    }
    *(ushort8_t*)(dst + g0) = o;
  }
}

// ---------------- K5: out[b,n,co] = sum_{h,g} eigN[b,h,n,g]*M2T[b,co,h*64+g] + out_b -----
__launch_bounds__(256)
__global__ void k_out(const unsigned short* __restrict__ eigN,
                      const unsigned short* __restrict__ m2t,
                      const float* __restrict__ outb,
                      float* __restrict__ out, int b0) {
  const int ct = blockIdx.x, mt = blockIdx.y, b = blockIdx.z;
  const int w = threadIdx.x >> 6, lane = threadIdx.x & 63;
  const int wm = w >> 1, wn = w & 1;
  const int arow = lane & 15, koff = (lane >> 4) * 8;
  const int co0 = ct * 128 + wn * 64;
  const int n0 = mt * 128 + wm * 64;
  f32x4 acc[4][4] = {};
  const unsigned short* ebase = eigN + (int64_t)b * NH * NPAD * 64;
  const unsigned short* mbase = m2t + (int64_t)b * 256 * 512;
  for (int ks = 0; ks < 16; ++ks) {
    const int hh = ks >> 1;
    const int g0 = (ks & 1) * 32 + koff;
    bf16x8 av[4], bv[4];
    #pragma unroll
    for (int mg = 0; mg < 4; ++mg) {
      int n = n0 + mg * 16 + arow;
      if (n > NPAD - 1) n = NPAD - 1;   // clamped rows read zeros; outputs masked below
      av[mg] = *(const bf16x8*)(ebase + ((int64_t)hh * NPAD + n) * 64 + g0);
    }
    #pragma unroll
    for (int ng = 0; ng < 4; ++ng)
      bv[ng] = *(const bf16x8*)(mbase + (int64_t)(co0 + ng * 16 + arow) * 512 + ks * 32 + koff);
    #pragma unroll
    for (int mg = 0; mg < 4; ++mg)
      #pragma unroll
      for (int ng = 0; ng < 4; ++ng)
        acc[mg][ng] = __builtin_amdgcn_mfma_f32_16x16x32_bf16(av[mg], bv[ng], acc[mg][ng], 0, 0, 0);
  }
  #pragma unroll
  for (int mg = 0; mg < 4; ++mg) {
    const int nr = n0 + mg * 16 + ((lane >> 4) << 2);
    #pragma unroll
    for (int ng = 0; ng < 4; ++ng) {
      const int co = co0 + ng * 16 + arow;
      const float bv = outb[co];
      #pragma unroll
      for (int r = 0; r < 4; ++r) {
        if (nr + r < NN)
          out[((int64_t)(b0 + b) * NN + nr + r) * 256 + co] = acc[mg][ng][r] + bv;
      }
    }
  }
}

extern "C" void kernel_launch(void* const* d_in, const int* in_sizes, int n_in,
                              void* d_out, int out_size, void* d_ws, size_t ws_size,
                              hipStream_t stream) {
  const float* x     = (const float*)d_in[0];
  const float* fxw   = (const float*)d_in[1];
  const float* fxb   = (const float*)d_in[2];
  const float* xw    = (const float*)d_in[3];
  const float* xb    = (const float*)d_in[4];
  const float* gw    = (const float*)d_in[5];
  const float* gb    = (const float*)d_in[6];
  const float* temp  = (const float*)d_in[7];
  const float* gamma = (const float*)d_in[8];
  const float* beta  = (const float*)d_in[9];
  const float* mlp   = (const float*)d_in[10];
  const float* outw  = (const float*)d_in[11];
  const float* outb  = (const float*)d_in[12];
  const float* inver = (const float*)d_in[13];
  float* out = (float*)d_out;
  char* ws = (char*)d_ws;
  (void)in_sizes; (void)n_in; (void)out_size;

  // ---- pick batch-chunk size CB by available workspace ----
  // need(CB) = 4,993,024 fixed + CB * (xpad 1,740,288 + m2t 262,144 + 4x 3,211,264)
  //          = 4,993,024 + CB * 14,847,488
  int CB = 1;
  {
    const int cands[6] = {32, 16, 8, 4, 2, 1};
    for (int i = 0; i < 6; ++i) {
      unsigned long long need = 4993024ull + (unsigned long long)cands[i] * 14847488ull;
      if (need <= (unsigned long long)ws_size) { CB = cands[i]; break; }
    }
  }

  // ---- fixed buffers ----
  unsigned short* Wb   = (unsigned short*)(ws + 0);         // 4,718,592
  float*          bias = (float*)(ws + 4718592);            // 4,096
  unsigned short* gwb  = (unsigned short*)(ws + 4722688);   // 8,192
  unsigned short* P    = (unsigned short*)(ws + 4730880);   // 262,144
  // ---- per-chunk buffers ----
  const size_t F0      = 4993024;
  const size_t szXpad  = (size_t)CB * 1740288;  // CB*103*33*256*2
  const size_t szM2t   = (size_t)CB * 262144;   // CB*256*512*2
  const size_t szBig   = (size_t)CB * 3211264;  // CB*8*64*3136*2
  unsigned short* xpad = (unsigned short*)(ws + F0);
  float*          part = (float*)(ws + F0);     // aliases xpad (dead after k_conv)
  unsigned short* m2t  = (unsigned short*)(ws + F0 + szXpad);
  unsigned short* fxT  = (unsigned short*)(ws + F0 + szXpad + szM2t);
  unsigned short* xmid = (unsigned short*)(ws + F0 + szXpad + szM2t + szBig);
  unsigned short* eigT = (unsigned short*)(ws + F0 + szXpad + szM2t + 2 * szBig);
  unsigned short* eigN = (unsigned short*)(ws + F0 + szXpad + szM2t + 3 * szBig);

  k_wpack<<<dim3(9216), dim3(256), 0, stream>>>(fxw, xw, fxb, xb, gw, Wb, bias, gwb);
  k_pprep<<<dim3(512), dim3(256), 0, stream>>>(mlp, outw, P);

  const int padBlocks = (CB * 217536 + 255) / 256;
  for (int b0 = 0; b0 < BB; b0 += CB) {
    k_pad<<<dim3(padBlocks), dim3(256), 0, stream>>>(x, xpad, b0, CB);
    k_padzero<<<dim3(CB * 10), dim3(256), 0, stream>>>(fxT, xmid, CB);
    k_conv<<<dim3(8, 25, CB), dim3(256), 0, stream>>>(xpad, Wb, bias, fxT, xmid);
    k_eig<<<dim3(49, 8, CB), dim3(256), 0, stream>>>(xmid, gwb, gb, temp, inver, eigT, eigN);
    k_spec<<<dim3(2, 8, CB), dim3(256), 0, stream>>>(eigT, fxT, part);
    k_ln<<<dim3(CB * 8), dim3(256), 0, stream>>>(part, gamma, beta, P, m2t);
    k_out<<<dim3(2, 25, CB), dim3(256), 0, stream>>>(eigN, m2t, outb, out, b0);
  }
}

// Round 3
// 1175.594 us; speedup vs baseline: 1.0546x; 1.0546x over previous
//
#include <hip/hip_runtime.h>
#include <hip/hip_bf16.h>
#include <stdint.h>

#define HH 101
#define WW 31
#define NN 3131
#define NPAD 3136
#define BB 32
#define NH 8
#define CDIM 256
#define GG 64
#define HP 103
#define WP 33

typedef __attribute__((ext_vector_type(8))) short bf16x8;
typedef __attribute__((ext_vector_type(4))) float f32x4;
typedef __attribute__((ext_vector_type(4))) unsigned short ushort4_t;
typedef __attribute__((ext_vector_type(8))) unsigned short ushort8_t;
typedef __attribute__((ext_vector_type(4))) float float4_t;

static __device__ __forceinline__ unsigned short f2bf(float f) {
  union { float f; uint32_t u; } v; v.f = f;
  uint32_t u = v.u;
  return (unsigned short)((u + 0x7fffu + ((u >> 16) & 1u)) >> 16);
}
static __device__ __forceinline__ float bf2f(unsigned short h) {
  union { uint32_t u; float f; } v; v.u = ((uint32_t)h) << 16;
  return v.f;
}
static __device__ __forceinline__ void gload_lds16(const void* g, void* l) {
  __builtin_amdgcn_global_load_lds((const __attribute__((address_space(1))) void*)g,
                                   (__attribute__((address_space(3))) void*)l, 16, 0, 0);
}
// m204 bijective XCD swizzle: hardware round-robins consecutive blockIdx across
// 8 XCDs; remap so each XCD gets a CONTIGUOUS chunk of the work space.
static __device__ __forceinline__ int xcd_swz(int bid, int nwg) {
  int q = nwg >> 3, r = nwg & 7;
  int xcd = bid & 7, pos = bid >> 3;
  int base = (xcd < r) ? xcd * (q + 1) : r * (q + 1) + (xcd - r) * q;
  return base + pos;
}

// ---------------- K0: pad + cast x -> bf16 (CB, HP, WP, C), no div/mod ----------------
__global__ void k_pad(const float* __restrict__ x, unsigned short* __restrict__ xpad, int b0) {
  const int xx = blockIdx.x, yy = blockIdx.y, b = blockIdx.z;
  const int t = threadIdx.x; // 64 threads, 4 channels each
  ushort4_t o; o.x = 0; o.y = 0; o.z = 0; o.w = 0;
  if (yy >= 1 && yy <= HH && xx >= 1 && xx <= WW) {
    const int n = (yy - 1) * WW + (xx - 1);
    const float4_t v = *(const float4_t*)(x + (((int64_t)(b0 + b) * NN + n) * CDIM + t * 4));
    o.x = f2bf(v.x); o.y = f2bf(v.y); o.z = f2bf(v.z); o.w = f2bf(v.w);
  }
  *(ushort4_t*)(xpad + (((int64_t)b * HP + yy) * WP + xx) * CDIM + t * 4) = o;
}

// ---------------- K1: pack conv weights Wb[t][co(1024)][cin] bf16, bias, gate_w bf16 --------
__global__ void k_wpack(const float* __restrict__ fxw, const float* __restrict__ xw,
                        const float* __restrict__ fxb, const float* __restrict__ xb,
                        const float* __restrict__ gw,
                        unsigned short* __restrict__ Wb, float* __restrict__ bias,
                        unsigned short* __restrict__ gwb) {
  int tid = blockIdx.x * blockDim.x + threadIdx.x;
  const int total = 9 * 1024 * 256;
  if (tid < total) {
    int cin = tid & 255; int rest = tid >> 8; int co = rest & 1023; int t = rest >> 10;
    float v = (co < 512) ? fxw[(int64_t)co * 2304 + cin * 9 + t]
                         : xw[(int64_t)(co - 512) * 2304 + cin * 9 + t];
    Wb[tid] = f2bf(v);
  }
  if (tid < 1024) bias[tid] = (tid < 512) ? fxb[tid] : xb[tid - 512];
  if (tid < 4096) gwb[tid] = f2bf(gw[tid]);
}

// ---------------- K1b: P[h][i][co] = sum_o mlp_w[i][o] * out_w[co][h*64+o] (bf16) ----------
__global__ void k_pprep(const float* __restrict__ mlp, const float* __restrict__ outw,
                        unsigned short* __restrict__ P) {
  int h = blockIdx.x >> 6, i = blockIdx.x & 63, co = threadIdx.x;
  float a = 0.f;
  for (int c = 0; c < 64; ++c) a += mlp[i * 64 + c] * outw[(int64_t)co * 512 + h * 64 + c];
  P[((int64_t)h * 64 + i) * 256 + co] = f2bf(a);
}

// ---------------- K1c: zero pad tails of fxT (cols) and xmid (rows), per chunk ----------
__global__ void k_padzero(unsigned short* __restrict__ fxT, unsigned short* __restrict__ xmid,
                          int CB) {
  int tid = blockIdx.x * blockDim.x + threadIdx.x;
  if (tid >= CB * 2560) return;
  {
    int j = tid % 5; int rc = tid / 5; // rc < CB*512 = (b*8+h)*64+c
    fxT[(int64_t)rc * NPAD + NN + j] = 0;
  }
  {
    int d = tid & 63; int rest = tid >> 6; // rest < CB*40
    int j = rest % 5; int bh = rest / 5;   // bh < CB*8
    xmid[((int64_t)bh * NPAD + NN + j) * 64 + d] = 0;
  }
}

// ---------------- K2: fused implicit-GEMM conv (both convs, N=1024) ----------------
// 1D grid 200*CB, XCD-swizzled; decode order: b outer, bx middle, mt inner so each
// XCD keeps {A-batch 1.74MB + ~3 B-tiles} < 4MB L2 resident.
__launch_bounds__(256)
__global__ void k_conv(const unsigned short* __restrict__ xpad,
                       const unsigned short* __restrict__ Wb,
                       const float* __restrict__ bias,
                       unsigned short* __restrict__ fxT,
                       unsigned short* __restrict__ xmid) {
  const int swz = xcd_swz(blockIdx.x, gridDim.x);
  const int mt = swz % 25;
  const int bx = (swz / 25) & 7;
  const int b  = swz / 200;
  const int tid = threadIdx.x;
  const int w = tid >> 6, lane = tid & 63;
  __shared__ unsigned short Als[128 * 32];
  __shared__ unsigned short Bls[128 * 32];

  const int chunk = lane & 3;
  const int r1 = w * 16 + (lane >> 2);
  const int r2 = 64 + r1;
  int n1 = mt * 128 + r1; if (n1 >= NN) n1 = NN - 1;
  int n2 = mt * 128 + r2; if (n2 >= NN) n2 = NN - 1;
  const int y1 = n1 / WW, x1 = n1 % WW;
  const int y2 = n2 / WW, x2 = n2 % WW;
  const unsigned short* aB1 = xpad + ((int64_t)(b * HP + y1) * WP + x1) * CDIM + chunk * 8;
  const unsigned short* aB2 = xpad + ((int64_t)(b * HP + y2) * WP + x2) * CDIM + chunk * 8;
  const int co0 = bx * 128;
  const unsigned short* bB1 = Wb + (int64_t)(co0 + r1) * CDIM + chunk * 8;
  const unsigned short* bB2 = Wb + (int64_t)(co0 + r2) * CDIM + chunk * 8;

  const int wm = w >> 1, wn = w & 1;
  const int arow = lane & 15;
  const int koff = (lane >> 4) * 8;

  f32x4 acc[4][4] = {};

  for (int ks = 0; ks < 72; ++ks) {
    const int t = ks >> 3;
    const int cin0 = (ks & 7) << 5;
    const int dy = t / 3, dx = t % 3;
    const int aoff = (dy * WP + dx) * CDIM + cin0;
    const int boff = t * 1024 * CDIM + cin0;
    __syncthreads();
    gload_lds16(aB1 + aoff, &Als[w * 512]);
    gload_lds16(aB2 + aoff, &Als[(4 + w) * 512]);
    gload_lds16(bB1 + boff, &Bls[w * 512]);
    gload_lds16(bB2 + boff, &Bls[(4 + w) * 512]);
    __syncthreads();
    bf16x8 av[4], bv[4];
    #pragma unroll
    for (int mg = 0; mg < 4; ++mg)
      av[mg] = *(const bf16x8*)&Als[(wm * 64 + mg * 16 + arow) * 32 + koff];
    #pragma unroll
    for (int ng = 0; ng < 4; ++ng)
      bv[ng] = *(const bf16x8*)&Bls[(wn * 64 + ng * 16 + arow) * 32 + koff];
    #pragma unroll
    for (int mg = 0; mg < 4; ++mg)
      #pragma unroll
      for (int ng = 0; ng < 4; ++ng)
        acc[mg][ng] = __builtin_amdgcn_mfma_f32_16x16x32_bf16(av[mg], bv[ng], acc[mg][ng], 0, 0, 0);
  }

  #pragma unroll
  for (int mg = 0; mg < 4; ++mg) {
    const int nr = mt * 128 + wm * 64 + mg * 16 + ((lane >> 4) << 2);
    #pragma unroll
    for (int ng = 0; ng < 4; ++ng) {
      const int co = co0 + wn * 64 + ng * 16 + arow;
      const float bvs = bias[co];
      const float v0 = acc[mg][ng][0] + bvs;
      const float v1 = acc[mg][ng][1] + bvs;
      const float v2 = acc[mg][ng][2] + bvs;
      const float v3 = acc[mg][ng][3] + bvs;
      if (co < 512) {
        const int h = co >> 6, c = co & 63;
        unsigned short* dst = fxT + ((int64_t)((b * NH + h) * 64 + c)) * NPAD + nr;
        if (nr + 3 < NN) {
          ushort4_t o; o.x = f2bf(v0); o.y = f2bf(v1); o.z = f2bf(v2); o.w = f2bf(v3);
          *(ushort4_t*)dst = o;
        } else {
          if (nr + 0 < NN) dst[0] = f2bf(v0);
          if (nr + 1 < NN) dst[1] = f2bf(v1);
          if (nr + 2 < NN) dst[2] = f2bf(v2);
          if (nr + 3 < NN) dst[3] = f2bf(v3);
        }
      } else {
        const int h = (co >> 6) & 7, d = co & 63;
        unsigned short* dst = xmid + ((int64_t)(b * NH + h) * NPAD + nr) * 64 + d;
        if (nr + 0 < NN) dst[0] = f2bf(v0);
        if (nr + 1 < NN) dst[64] = f2bf(v1);
        if (nr + 2 < NN) dst[128] = f2bf(v2);
        if (nr + 3 < NN) dst[192] = f2bf(v3);
      }
    }
  }
}

// ---------------- K3: logits MFMA + softmax + eigens; LDS-staged coalesced stores -------
__global__ void k_eig(const unsigned short* __restrict__ xmid,
                      const unsigned short* __restrict__ gwb,
                      const float* __restrict__ gateb,
                      const float* __restrict__ temperature,
                      const float* __restrict__ inver,
                      unsigned short* __restrict__ eigT,
                      unsigned short* __restrict__ eigN) {
  __shared__ unsigned short egN[64 * 72];   // [n_local][g], pad-72 stride
  __shared__ unsigned short egT[64 * 72];   // [g][n_local]
  const int nt = blockIdx.x, h = blockIdx.y, b = blockIdx.z;
  const int tid = threadIdx.x;
  const int w = tid >> 6, lane = tid & 63;
  const int n0 = nt * 64 + w * 16;
  const int bh = b * NH + h;
  float tv = temperature[h];
  tv = fminf(fmaxf(tv, 0.1f), 5.0f);
  const float itemp = 1.0f / tv;
  const int arow = lane & 15;
  const int koff = (lane >> 4) * 8;
  const unsigned short* aptr = xmid + ((int64_t)bh * NPAD + (n0 + arow)) * 64 + koff;
  bf16x8 a0 = *(const bf16x8*)(aptr);
  bf16x8 a1 = *(const bf16x8*)(aptr + 32);
  f32x4 acc[4] = {};
  #pragma unroll
  for (int ng = 0; ng < 4; ++ng) {
    const unsigned short* bptr = gwb + (ng * 16 + arow) * 64 + koff;
    bf16x8 b0 = *(const bf16x8*)(bptr);
    bf16x8 b1 = *(const bf16x8*)(bptr + 32);
    acc[ng] = __builtin_amdgcn_mfma_f32_16x16x32_bf16(a0, b0, acc[ng], 0, 0, 0);
    acc[ng] = __builtin_amdgcn_mfma_f32_16x16x32_bf16(a1, b1, acc[ng], 0, 0, 0);
  }
  #pragma unroll
  for (int r = 0; r < 4; ++r) {
    const int nl = w * 16 + ((lane >> 4) << 2) + r;   // row within block's 64
    const int n = nt * 64 + nl;
    float vals[4];
    #pragma unroll
    for (int ng = 0; ng < 4; ++ng) vals[ng] = (acc[ng][r] + gateb[ng * 16 + arow]) * itemp;
    float mx = fmaxf(fmaxf(vals[0], vals[1]), fmaxf(vals[2], vals[3]));
    #pragma unroll
    for (int s = 1; s < 16; s <<= 1) mx = fmaxf(mx, __shfl_xor(mx, s));
    float ex[4]; float sum = 0.f;
    #pragma unroll
    for (int ng = 0; ng < 4; ++ng) { ex[ng] = __expf(vals[ng] - mx); sum += ex[ng]; }
    #pragma unroll
    for (int s = 1; s < 16; s <<= 1) sum += __shfl_xor(sum, s);
    const float inv = 1.0f / sum;
    const bool valid = (n < NN);
    #pragma unroll
    for (int ng = 0; ng < 4; ++ng) {
      const int g = ng * 16 + arow;
      float iv = valid ? inver[(int64_t)n * GG + g] : 0.f;
      unsigned short u = valid ? f2bf(ex[ng] * inv * iv) : (unsigned short)0;
      egN[nl * 72 + g] = u;
      egT[g * 72 + nl] = u;
    }
  }
  __syncthreads();
  const int row = tid >> 2, c0 = (tid & 3) << 4;
  {
    ushort8_t v0 = *(ushort8_t*)&egN[row * 72 + c0];
    ushort8_t v1 = *(ushort8_t*)&egN[row * 72 + c0 + 8];
    unsigned short* dst = eigN + ((int64_t)bh * NPAD + nt * 64 + row) * 64 + c0;
    *(ushort8_t*)dst = v0; *(ushort8_t*)(dst + 8) = v1;
  }
  {
    ushort8_t v0 = *(ushort8_t*)&egT[row * 72 + c0];
    ushort8_t v1 = *(ushort8_t*)&egT[row * 72 + c0 + 8];
    unsigned short* dst = eigT + ((int64_t)(bh * 64 + row)) * NPAD + nt * 64 + c0;
    *(ushort8_t*)dst = v0; *(ushort8_t*)(dst + 8) = v1;
  }
}

// ---------------- K4a: spec partials: spec[g,c] = sum_n eigT[g,n]*fxT[c,n] ----------------
__global__ void k_spec(const unsigned short* __restrict__ eigT,
                       const unsigned short* __restrict__ fxT,
                       float* __restrict__ part) {
  const int half = blockIdx.x, h = blockIdx.y, b = blockIdx.z;
  const int w = threadIdx.x >> 6, lane = threadIdx.x & 63;
  const int s = half * 4 + w;
  const int bh = b * NH + h;
  const int ks0 = (98 * s) >> 3, ks1 = (98 * (s + 1)) >> 3;
  const int arow = lane & 15, koff = (lane >> 4) * 8;
  const unsigned short* eb = eigT + (int64_t)bh * 64 * NPAD;
  const unsigned short* fb = fxT + (int64_t)bh * 64 * NPAD;
  f32x4 acc[4][4] = {};
  for (int ks = ks0; ks < ks1; ++ks) {
    const int k0 = ks * 32 + koff;
    bf16x8 av[4], bv[4];
    #pragma unroll
    for (int mg = 0; mg < 4; ++mg) av[mg] = *(const bf16x8*)(eb + (int64_t)(mg * 16 + arow) * NPAD + k0);
    #pragma unroll
    for (int ng = 0; ng < 4; ++ng) bv[ng] = *(const bf16x8*)(fb + (int64_t)(ng * 16 + arow) * NPAD + k0);
    #pragma unroll
    for (int mg = 0; mg < 4; ++mg)
      #pragma unroll
      for (int ng = 0; ng < 4; ++ng)
        acc[mg][ng] = __builtin_amdgcn_mfma_f32_16x16x32_bf16(av[mg], bv[ng], acc[mg][ng], 0, 0, 0);
  }
  float* pb = part + ((int64_t)bh * 8 + s) * 4096;
  #pragma unroll
  for (int mg = 0; mg < 4; ++mg)
    #pragma unroll
    for (int ng = 0; ng < 4; ++ng)
      #pragma unroll
      for (int r = 0; r < 4; ++r)
        pb[(mg * 16 + ((lane >> 4) << 2) + r) * 64 + ng * 16 + arow] = acc[mg][ng][r];
}

// ---------------- K4b: sum partials, LayerNorm, M2T = (LN(spec) @ P_h)^T bf16 ------------
__global__ void k_ln(const float* __restrict__ part,
                     const float* __restrict__ gamma, const float* __restrict__ beta,
                     const unsigned short* __restrict__ P,
                     unsigned short* __restrict__ m2t) {
  __shared__ float spec[4096];
  __shared__ float red[8];
  __shared__ unsigned short Pl[64 * 256];
  const int bh = blockIdx.x, tid = threadIdx.x;
  const int h = bh & 7;
  const float* pb = part + (int64_t)bh * 8 * 4096;
  float lsum = 0.f, lsq = 0.f;
  for (int e = tid; e < 4096; e += 256) {
    float v = 0.f;
    #pragma unroll
    for (int s = 0; s < 8; ++s) v += pb[s * 4096 + e];
    spec[e] = v; lsum += v; lsq += v * v;
  }
  for (int e = tid; e < 64 * 256; e += 256) Pl[e] = P[(int64_t)h * 64 * 256 + e];
  #pragma unroll
  for (int s = 1; s < 64; s <<= 1) { lsum += __shfl_xor(lsum, s); lsq += __shfl_xor(lsq, s); }
  const int w = tid >> 6, lane = tid & 63;
  if (lane == 0) { red[w] = lsum; red[4 + w] = lsq; }
  __syncthreads();
  const float tsum = red[0] + red[1] + red[2] + red[3];
  const float tsq = red[4] + red[5] + red[6] + red[7];
  const float mu = tsum * (1.0f / 4096.0f);
  const float var = tsq * (1.0f / 4096.0f) - mu * mu;
  const float rs = rsqrtf(var + 1e-5f);
  for (int e = tid; e < 4096; e += 256) {
    spec[e] = (spec[e] - mu) * rs * gamma[e] + beta[e];
  }
  __syncthreads();
  const int co = tid;
  const int b_ = bh >> 3;
  unsigned short* dst = m2t + ((int64_t)(b_ * 256 + co)) * 512 + h * 64;
  float pr[64];
  #pragma unroll
  for (int i = 0; i < 64; ++i) pr[i] = bf2f(Pl[i * 256 + co]);
  for (int g0 = 0; g0 < 64; g0 += 8) {
    ushort8_t o;
    #pragma unroll
    for (int gi = 0; gi < 8; ++gi) {
      float a = 0.f;
      #pragma unroll
      for (int i = 0; i < 64; ++i) a += spec[(g0 + gi) * 64 + i] * pr[i];
      o[gi] = f2bf(a);
    }
    *(ushort8_t*)(dst + g0) = o;
  }
}

// ---------------- K5: out[b,n,co] = sum_{h,g} eigN[b,h,n,g]*M2T[b,co,h*64+g] + out_b -----
// 1D grid 50*CB, XCD-swizzled (2 ct-blocks share the A-panel -> same XCD).
__launch_bounds__(256)
__global__ void k_out(const unsigned short* __restrict__ eigN,
                      const unsigned short* __restrict__ m2t,
                      const float* __restrict__ outb,
                      float* __restrict__ out, int b0) {
  const int swz = xcd_swz(blockIdx.x, gridDim.x);
  const int ct = swz & 1;
  const int mt = (swz >> 1) % 25;
  const int b  = swz / 50;
  const int w = threadIdx.x >> 6, lane = threadIdx.x & 63;
  const int wm = w >> 1, wn = w & 1;
  const int arow = lane & 15, koff = (lane >> 4) * 8;
  const int co0 = ct * 128 + wn * 64;
  const int n0 = mt * 128 + wm * 64;
  f32x4 acc[4][4] = {};
  const unsigned short* ebase = eigN + (int64_t)b * NH * NPAD * 64;
  const unsigned short* mbase = m2t + (int64_t)b * 256 * 512;
  for (int ks = 0; ks < 16; ++ks) {
    const int hh = ks >> 1;
    const int g0 = (ks & 1) * 32 + koff;
    bf16x8 av[4], bv[4];
    #pragma unroll
    for (int mg = 0; mg < 4; ++mg) {
      int n = n0 + mg * 16 + arow;
      if (n > NPAD - 1) n = NPAD - 1;   // clamped rows read zeros; outputs masked below
      av[mg] = *(const bf16x8*)(ebase + ((int64_t)hh * NPAD + n) * 64 + g0);
    }
    #pragma unroll
    for (int ng = 0; ng < 4; ++ng)
      bv[ng] = *(const bf16x8*)(mbase + (int64_t)(co0 + ng * 16 + arow) * 512 + ks * 32 + koff);
    #pragma unroll
    for (int mg = 0; mg < 4; ++mg)
      #pragma unroll
      for (int ng = 0; ng < 4; ++ng)
        acc[mg][ng] = __builtin_amdgcn_mfma_f32_16x16x32_bf16(av[mg], bv[ng], acc[mg][ng], 0, 0, 0);
  }
  #pragma unroll
  for (int mg = 0; mg < 4; ++mg) {
    const int nr = n0 + mg * 16 + ((lane >> 4) << 2);
    #pragma unroll
    for (int ng = 0; ng < 4; ++ng) {
      const int co = co0 + ng * 16 + arow;
      const float bv = outb[co];
      #pragma unroll
      for (int r = 0; r < 4; ++r) {
        if (nr + r < NN)
          out[((int64_t)(b0 + b) * NN + nr + r) * 256 + co] = acc[mg][ng][r] + bv;
      }
    }
  }
}

extern "C" void kernel_launch(void* const* d_in, const int* in_sizes, int n_in,
                              void* d_out, int out_size, void* d_ws, size_t ws_size,
                              hipStream_t stream) {
  const float* x     = (const float*)d_in[0];
  const float* fxw   = (const float*)d_in[1];
  const float* fxb   = (const float*)d_in[2];
  const float* xw    = (const float*)d_in[3];
  const float* xb    = (const float*)d_in[4];
  const float* gw    = (const float*)d_in[5];
  const float* gb    = (const float*)d_in[6];
  const float* temp  = (const float*)d_in[7];
  const float* gamma = (const float*)d_in[8];
  const float* beta  = (const float*)d_in[9];
  const float* mlp   = (const float*)d_in[10];
  const float* outw  = (const float*)d_in[11];
  const float* outb  = (const float*)d_in[12];
  const float* inver = (const float*)d_in[13];
  float* out = (float*)d_out;
  char* ws = (char*)d_ws;
  (void)in_sizes; (void)n_in; (void)out_size;

  // ---- pick batch-chunk size CB by available workspace ----
  int CB = 1;
  {
    const int cands[6] = {32, 16, 8, 4, 2, 1};
    for (int i = 0; i < 6; ++i) {
      unsigned long long need = 4993024ull + (unsigned long long)cands[i] * 14847488ull;
      if (need <= (unsigned long long)ws_size) { CB = cands[i]; break; }
    }
  }

  // ---- fixed buffers ----
  unsigned short* Wb   = (unsigned short*)(ws + 0);         // 4,718,592
  float*          bias = (float*)(ws + 4718592);            // 4,096
  unsigned short* gwb  = (unsigned short*)(ws + 4722688);   // 8,192
  unsigned short* P    = (unsigned short*)(ws + 4730880);   // 262,144
  // ---- per-chunk buffers ----
  const size_t F0      = 4993024;
  const size_t szXpad  = (size_t)CB * 1740288;  // CB*103*33*256*2
  const size_t szM2t   = (size_t)CB * 262144;   // CB*256*512*2
  const size_t szBig   = (size_t)CB * 3211264;  // CB*8*64*3136*2
  unsigned short* xpad = (unsigned short*)(ws + F0);
  float*          part = (float*)(ws + F0);     // aliases xpad (dead after k_conv)
  unsigned short* m2t  = (unsigned short*)(ws + F0 + szXpad);
  unsigned short* fxT  = (unsigned short*)(ws + F0 + szXpad + szM2t);
  unsigned short* xmid = (unsigned short*)(ws + F0 + szXpad + szM2t + szBig);
  unsigned short* eigT = (unsigned short*)(ws + F0 + szXpad + szM2t + 2 * szBig);
  unsigned short* eigN = (unsigned short*)(ws + F0 + szXpad + szM2t + 3 * szBig);

  k_wpack<<<dim3(9216), dim3(256), 0, stream>>>(fxw, xw, fxb, xb, gw, Wb, bias, gwb);
  k_pprep<<<dim3(512), dim3(256), 0, stream>>>(mlp, outw, P);

  for (int b0 = 0; b0 < BB; b0 += CB) {
    k_pad<<<dim3(WP, HP, CB), dim3(64), 0, stream>>>(x, xpad, b0);
    k_padzero<<<dim3(CB * 10), dim3(256), 0, stream>>>(fxT, xmid, CB);
    k_conv<<<dim3(200 * CB), dim3(256), 0, stream>>>(xpad, Wb, bias, fxT, xmid);
    k_eig<<<dim3(49, 8, CB), dim3(256), 0, stream>>>(xmid, gwb, gb, temp, inver, eigT, eigN);
    k_spec<<<dim3(2, 8, CB), dim3(256), 0, stream>>>(eigT, fxT, part);
    k_ln<<<dim3(CB * 8), dim3(256), 0, stream>>>(part, gamma, beta, P, m2t);
    k_out<<<dim3(50 * CB), dim3(256), 0, stream>>>(eigN, m2t, outb, out, b0);
  }
}

// Round 4
// 1147.459 us; speedup vs baseline: 1.0804x; 1.0245x over previous
//
#include <hip/hip_runtime.h>
#include <hip/hip_bf16.h>
#include <stdint.h>

#define HH 101
#define WW 31
#define NN 3131
#define NPAD 3136
#define BB 32
#define NH 8
#define CDIM 256
#define GG 64
#define HP 103
#define WP 33

typedef __attribute__((ext_vector_type(8))) short bf16x8;
typedef __attribute__((ext_vector_type(4))) float f32x4;
typedef __attribute__((ext_vector_type(4))) unsigned short ushort4_t;
typedef __attribute__((ext_vector_type(8))) unsigned short ushort8_t;
typedef __attribute__((ext_vector_type(4))) float float4_t;

static __device__ __forceinline__ unsigned short f2bf(float f) {
  union { float f; uint32_t u; } v; v.f = f;
  uint32_t u = v.u;
  return (unsigned short)((u + 0x7fffu + ((u >> 16) & 1u)) >> 16);
}
static __device__ __forceinline__ float bf2f(unsigned short h) {
  union { uint32_t u; float f; } v; v.u = ((uint32_t)h) << 16;
  return v.f;
}
static __device__ __forceinline__ void gload_lds16(const void* g, void* l) {
  __builtin_amdgcn_global_load_lds((const __attribute__((address_space(1))) void*)g,
                                   (__attribute__((address_space(3))) void*)l, 16, 0, 0);
}
// m204 bijective XCD swizzle
static __device__ __forceinline__ int xcd_swz(int bid, int nwg) {
  int q = nwg >> 3, r = nwg & 7;
  int xcd = bid & 7, pos = bid >> 3;
  int base = (xcd < r) ? xcd * (q + 1) : r * (q + 1) + (xcd - r) * q;
  return base + pos;
}

// ---------------- K0: pad + cast x -> bf16 (CB, HP, WP, C) ----------------
__global__ void k_pad(const float* __restrict__ x, unsigned short* __restrict__ xpad, int b0) {
  const int xx = blockIdx.x, yy = blockIdx.y, b = blockIdx.z;
  const int t = threadIdx.x; // 64 threads, 4 channels each
  ushort4_t o; o.x = 0; o.y = 0; o.z = 0; o.w = 0;
  if (yy >= 1 && yy <= HH && xx >= 1 && xx <= WW) {
    const int n = (yy - 1) * WW + (xx - 1);
    const float4_t v = *(const float4_t*)(x + (((int64_t)(b0 + b) * NN + n) * CDIM + t * 4));
    o.x = f2bf(v.x); o.y = f2bf(v.y); o.z = f2bf(v.z); o.w = f2bf(v.w);
  }
  *(ushort4_t*)(xpad + (((int64_t)b * HP + yy) * WP + xx) * CDIM + t * 4) = o;
}

// ---------------- K1: pack conv weights Wb[t][co(1024)][cin] bf16, bias, gate_w bf16 ------
__global__ void k_wpack(const float* __restrict__ fxw, const float* __restrict__ xw,
                        const float* __restrict__ fxb, const float* __restrict__ xb,
                        const float* __restrict__ gw,
                        unsigned short* __restrict__ Wb, float* __restrict__ bias,
                        unsigned short* __restrict__ gwb) {
  int tid = blockIdx.x * blockDim.x + threadIdx.x;
  const int total = 9 * 1024 * 256;
  if (tid < total) {
    int cin = tid & 255; int rest = tid >> 8; int co = rest & 1023; int t = rest >> 10;
    float v = (co < 512) ? fxw[(int64_t)co * 2304 + cin * 9 + t]
                         : xw[(int64_t)(co - 512) * 2304 + cin * 9 + t];
    Wb[tid] = f2bf(v);
  }
  if (tid < 1024) bias[tid] = (tid < 512) ? fxb[tid] : xb[tid - 512];
  if (tid < 4096) gwb[tid] = f2bf(gw[tid]);
}

// ---------------- K1b: P[h][i][co] = sum_c mlp_w[i][c] * out_w[co][h*64+c] (bf16) ---------
__global__ void k_pprep(const float* __restrict__ mlp, const float* __restrict__ outw,
                        unsigned short* __restrict__ P) {
  int h = blockIdx.x >> 6, i = blockIdx.x & 63, co = threadIdx.x;
  float a = 0.f;
  for (int c = 0; c < 64; ++c) a += mlp[i * 64 + c] * outw[(int64_t)co * 512 + h * 64 + c];
  P[((int64_t)h * 64 + i) * 256 + co] = f2bf(a);
}

// ---------------- K1c: zero pad tails of fxT (cols) and xmid (rows) ----------
__global__ void k_padzero(unsigned short* __restrict__ fxT, unsigned short* __restrict__ xmid,
                          int CB) {
  int tid = blockIdx.x * blockDim.x + threadIdx.x;
  if (tid >= CB * 2560) return;
  {
    int j = tid % 5; int rc = tid / 5;
    fxT[(int64_t)rc * NPAD + NN + j] = 0;
  }
  {
    int d = tid & 63; int rest = tid >> 6;
    int j = rest % 5; int bh = rest / 5;
    xmid[((int64_t)bh * NPAD + NN + j) * 64 + d] = 0;
  }
}

// ---------------- K2: 256x256 deep-pipelined implicit-GEMM conv ----------------
// 8 waves (2M x 4N), BK=32, 4 LDS slots (128KB), prefetch distance 2 K-tiles,
// counted vmcnt(4) at K-tile entry (never 0 in loop), setprio around MFMA.
// LDS bank swizzle via pre-swizzled GLOBAL source (global_load_lds dest is linear):
// col16' = col16 ^ ((row ^ row>>2)&3)  -> 2-way max on ds_read_b128 (free).
static __device__ __forceinline__ void stage_a8(const unsigned short* aS0, const unsigned short* aS1,
                                                unsigned short* lds, int s, int wid, int kt) {
  const int t = kt >> 3;
  const int dy = (t >= 6) + (t >= 3);
  const int dx = t - dy * 3;
  const int aoff = (dy * WP + dx) * CDIM + (kt & 7) * 32;
  gload_lds16(aS0 + aoff, lds + s * 16384 + wid * 512);
  gload_lds16(aS1 + aoff, lds + s * 16384 + 4096 + wid * 512);
}
static __device__ __forceinline__ void stage_b8(const unsigned short* bS0, const unsigned short* bS1,
                                                unsigned short* lds, int s, int wid, int kt) {
  const int t = kt >> 3;
  const int boff = t * (1024 * CDIM) + (kt & 7) * 32;
  gload_lds16(bS0 + boff, lds + s * 16384 + 8192 + wid * 512);
  gload_lds16(bS1 + boff, lds + s * 16384 + 8192 + 4096 + wid * 512);
}

__launch_bounds__(512, 2)
__global__ void k_conv8(const unsigned short* __restrict__ xpad,
                        const unsigned short* __restrict__ Wb,
                        const float* __restrict__ bias,
                        unsigned short* __restrict__ fxT,
                        unsigned short* __restrict__ xmid) {
  extern __shared__ unsigned short lds[];   // 4 slots x (A 8192 + B 8192) elems = 128 KB
  const int swz = xcd_swz(blockIdx.x, gridDim.x);
  const int r   = swz % 52;
  const int b   = swz / 52;
  const int bx  = r & 3;         // 4 N-tiles of 256 (bx<2: fx, bx>=2: xmid)
  const int mt  = r >> 2;        // 13 M-tiles of 256
  const int tid = threadIdx.x, wid = tid >> 6, lane = tid & 63;
  const int wm = wid >> 2, wn = wid & 3;
  const int arow = lane & 15, col16 = lane >> 4;
  const int n00 = mt * 256, co00 = bx * 256;

  // staging lane constants (fixed rows per lane; swizzled source col)
  const int srow = wid * 16 + (lane >> 2);                       // 0..127
  const int tc   = ((lane & 3) ^ ((srow ^ (srow >> 2)) & 3)) * 8;
  int na0 = n00 + srow;        if (na0 >= NN) na0 = NN - 1;
  int na1 = n00 + srow + 128;  if (na1 >= NN) na1 = NN - 1;
  const int y0 = na0 / WW, x0v = na0 % WW;
  const int y1 = na1 / WW, x1v = na1 % WW;
  const unsigned short* aS0 = xpad + ((int64_t)(b * HP + y0) * WP + x0v) * CDIM + tc;
  const unsigned short* aS1 = xpad + ((int64_t)(b * HP + y1) * WP + x1v) * CDIM + tc;
  const unsigned short* bS0 = Wb + (int64_t)(co00 + srow) * CDIM + tc;
  const unsigned short* bS1 = Wb + (int64_t)(co00 + srow + 128) * CDIM + tc;

  // ds_read swizzled col offset (elems)
  const int rdcol = (col16 ^ ((arow ^ (arow >> 2)) & 3)) * 8;

  f32x4 acc[8][4] = {};

  // prologue: stage K-tiles 0,1 (queue: A0,B0,A1,B1 = 8 loads/wave)
  stage_a8(aS0, aS1, lds, 0, wid, 0); stage_b8(bS0, bS1, lds, 0, wid, 0);
  stage_a8(aS0, aS1, lds, 1, wid, 1); stage_b8(bS0, bS1, lds, 1, wid, 1);

  for (int kt = 0; kt < 72; ++kt) {
    const int s = kt & 3;
    const unsigned short* sA = lds + s * 16384;
    const unsigned short* sB = sA + 8192;
    const int s2  = (kt + 2) & 3;
    const int kt2 = (kt + 2 > 71) ? 71 : kt + 2;   // address clamp only (slot still rotates)

    // K-tile entry: drain own 4 oldest (this K-tile's stages), rendezvous.
    asm volatile("s_waitcnt vmcnt(4)" ::: "memory");
    __builtin_amdgcn_s_barrier();
    asm volatile("" ::: "memory");                  // block IR load-hoist above barrier
    __builtin_amdgcn_sched_barrier(0);

    bf16x8 av[8], bv0, bv1, bv2, bv3;
    #pragma unroll
    for (int mf = 0; mf < 8; ++mf)
      av[mf] = *(const bf16x8*)(sA + (wm * 128 + mf * 16 + arow) * 32 + rdcol);
    bv0 = *(const bf16x8*)(sB + (wn * 64 + 0 * 16 + arow) * 32 + rdcol);
    bv1 = *(const bf16x8*)(sB + (wn * 64 + 1 * 16 + arow) * 32 + rdcol);
    stage_a8(aS0, aS1, lds, s2, wid, kt2);
    __builtin_amdgcn_s_setprio(1);
    #pragma unroll
    for (int mf = 0; mf < 8; ++mf) {
      acc[mf][0] = __builtin_amdgcn_mfma_f32_16x16x32_bf16(av[mf], bv0, acc[mf][0], 0, 0, 0);
      acc[mf][1] = __builtin_amdgcn_mfma_f32_16x16x32_bf16(av[mf], bv1, acc[mf][1], 0, 0, 0);
    }
    __builtin_amdgcn_s_setprio(0);

    __builtin_amdgcn_s_barrier();                   // pacing barrier (phase split)
    asm volatile("" ::: "memory");
    __builtin_amdgcn_sched_barrier(0);

    bv2 = *(const bf16x8*)(sB + (wn * 64 + 2 * 16 + arow) * 32 + rdcol);
    bv3 = *(const bf16x8*)(sB + (wn * 64 + 3 * 16 + arow) * 32 + rdcol);
    stage_b8(bS0, bS1, lds, s2, wid, kt2);
    __builtin_amdgcn_s_setprio(1);
    #pragma unroll
    for (int mf = 0; mf < 8; ++mf) {
      acc[mf][2] = __builtin_amdgcn_mfma_f32_16x16x32_bf16(av[mf], bv2, acc[mf][2], 0, 0, 0);
      acc[mf][3] = __builtin_amdgcn_mfma_f32_16x16x32_bf16(av[mf], bv3, acc[mf][3], 0, 0, 0);
    }
    __builtin_amdgcn_s_setprio(0);
  }

  // pending tail stages must not land after LDS is re-allocated to another block
  asm volatile("s_waitcnt vmcnt(0)" ::: "memory");

  const int rowoff = col16 * 4;
  #pragma unroll
  for (int mf = 0; mf < 8; ++mf) {
    const int nr = n00 + wm * 128 + mf * 16 + rowoff;
    #pragma unroll
    for (int nf = 0; nf < 4; ++nf) {
      const int co = co00 + wn * 64 + nf * 16 + arow;
      const float bvs = bias[co];
      const float v0 = acc[mf][nf][0] + bvs;
      const float v1 = acc[mf][nf][1] + bvs;
      const float v2 = acc[mf][nf][2] + bvs;
      const float v3 = acc[mf][nf][3] + bvs;
      if (bx < 2) {
        const int h = co >> 6, c = co & 63;
        unsigned short* dst = fxT + ((int64_t)((b * NH + h) * 64 + c)) * NPAD + nr;
        if (nr + 3 < NN) {
          ushort4_t o; o.x = f2bf(v0); o.y = f2bf(v1); o.z = f2bf(v2); o.w = f2bf(v3);
          *(ushort4_t*)dst = o;
        } else {
          if (nr + 0 < NN) dst[0] = f2bf(v0);
          if (nr + 1 < NN) dst[1] = f2bf(v1);
          if (nr + 2 < NN) dst[2] = f2bf(v2);
          if (nr + 3 < NN) dst[3] = f2bf(v3);
        }
      } else {
        const int h = (co >> 6) & 7, d = co & 63;
        unsigned short* dst = xmid + ((int64_t)(b * NH + h) * NPAD + nr) * 64 + d;
        if (nr + 0 < NN) dst[0] = f2bf(v0);
        if (nr + 1 < NN) dst[64] = f2bf(v1);
        if (nr + 2 < NN) dst[128] = f2bf(v2);
        if (nr + 3 < NN) dst[192] = f2bf(v3);
      }
    }
  }
}

// ---------------- K3: logits MFMA + softmax + eigens; LDS-staged coalesced stores -------
__global__ void k_eig(const unsigned short* __restrict__ xmid,
                      const unsigned short* __restrict__ gwb,
                      const float* __restrict__ gateb,
                      const float* __restrict__ temperature,
                      const float* __restrict__ inver,
                      unsigned short* __restrict__ eigT,
                      unsigned short* __restrict__ eigN) {
  __shared__ unsigned short egN[64 * 72];
  __shared__ unsigned short egT[64 * 72];
  const int nt = blockIdx.x, h = blockIdx.y, b = blockIdx.z;
  const int tid = threadIdx.x;
  const int w = tid >> 6, lane = tid & 63;
  const int n0 = nt * 64 + w * 16;
  const int bh = b * NH + h;
  float tv = temperature[h];
  tv = fminf(fmaxf(tv, 0.1f), 5.0f);
  const float itemp = 1.0f / tv;
  const int arow = lane & 15;
  const int koff = (lane >> 4) * 8;
  const unsigned short* aptr = xmid + ((int64_t)bh * NPAD + (n0 + arow)) * 64 + koff;
  bf16x8 a0 = *(const bf16x8*)(aptr);
  bf16x8 a1 = *(const bf16x8*)(aptr + 32);
  f32x4 acc[4] = {};
  #pragma unroll
  for (int ng = 0; ng < 4; ++ng) {
    const unsigned short* bptr = gwb + (ng * 16 + arow) * 64 + koff;
    bf16x8 b0 = *(const bf16x8*)(bptr);
    bf16x8 b1 = *(const bf16x8*)(bptr + 32);
    acc[ng] = __builtin_amdgcn_mfma_f32_16x16x32_bf16(a0, b0, acc[ng], 0, 0, 0);
    acc[ng] = __builtin_amdgcn_mfma_f32_16x16x32_bf16(a1, b1, acc[ng], 0, 0, 0);
  }
  #pragma unroll
  for (int r = 0; r < 4; ++r) {
    const int nl = w * 16 + ((lane >> 4) << 2) + r;
    const int n = nt * 64 + nl;
    float vals[4];
    #pragma unroll
    for (int ng = 0; ng < 4; ++ng) vals[ng] = (acc[ng][r] + gateb[ng * 16 + arow]) * itemp;
    float mx = fmaxf(fmaxf(vals[0], vals[1]), fmaxf(vals[2], vals[3]));
    #pragma unroll
    for (int s = 1; s < 16; s <<= 1) mx = fmaxf(mx, __shfl_xor(mx, s));
    float ex[4]; float sum = 0.f;
    #pragma unroll
    for (int ng = 0; ng < 4; ++ng) { ex[ng] = __expf(vals[ng] - mx); sum += ex[ng]; }
    #pragma unroll
    for (int s = 1; s < 16; s <<= 1) sum += __shfl_xor(sum, s);
    const float inv = 1.0f / sum;
    const bool valid = (n < NN);
    #pragma unroll
    for (int ng = 0; ng < 4; ++ng) {
      const int g = ng * 16 + arow;
      float iv = valid ? inver[(int64_t)n * GG + g] : 0.f;
      unsigned short u = valid ? f2bf(ex[ng] * inv * iv) : (unsigned short)0;
      egN[nl * 72 + g] = u;
      egT[g * 72 + nl] = u;
    }
  }
  __syncthreads();
  const int row = tid >> 2, c0 = (tid & 3) << 4;
  {
    ushort8_t v0 = *(ushort8_t*)&egN[row * 72 + c0];
    ushort8_t v1 = *(ushort8_t*)&egN[row * 72 + c0 + 8];
    unsigned short* dst = eigN + ((int64_t)bh * NPAD + nt * 64 + row) * 64 + c0;
    *(ushort8_t*)dst = v0; *(ushort8_t*)(dst + 8) = v1;
  }
  {
    ushort8_t v0 = *(ushort8_t*)&egT[row * 72 + c0];
    ushort8_t v1 = *(ushort8_t*)&egT[row * 72 + c0 + 8];
    unsigned short* dst = eigT + ((int64_t)(bh * 64 + row)) * NPAD + nt * 64 + c0;
    *(ushort8_t*)dst = v0; *(ushort8_t*)(dst + 8) = v1;
  }
}

// ---------------- K4a: spec partials ----------------
__global__ void k_spec(const unsigned short* __restrict__ eigT,
                       const unsigned short* __restrict__ fxT,
                       float* __restrict__ part) {
  const int half = blockIdx.x, h = blockIdx.y, b = blockIdx.z;
  const int w = threadIdx.x >> 6, lane = threadIdx.x & 63;
  const int s = half * 4 + w;
  const int bh = b * NH + h;
  const int ks0 = (98 * s) >> 3, ks1 = (98 * (s + 1)) >> 3;
  const int arow = lane & 15, koff = (lane >> 4) * 8;
  const unsigned short* eb = eigT + (int64_t)bh * 64 * NPAD;
  const unsigned short* fb = fxT + (int64_t)bh * 64 * NPAD;
  f32x4 acc[4][4] = {};
  for (int ks = ks0; ks < ks1; ++ks) {
    const int k0 = ks * 32 + koff;
    bf16x8 av[4], bv[4];
    #pragma unroll
    for (int mg = 0; mg < 4; ++mg) av[mg] = *(const bf16x8*)(eb + (int64_t)(mg * 16 + arow) * NPAD + k0);
    #pragma unroll
    for (int ng = 0; ng < 4; ++ng) bv[ng] = *(const bf16x8*)(fb + (int64_t)(ng * 16 + arow) * NPAD + k0);
    #pragma unroll
    for (int mg = 0; mg < 4; ++mg)
      #pragma unroll
      for (int ng = 0; ng < 4; ++ng)
        acc[mg][ng] = __builtin_amdgcn_mfma_f32_16x16x32_bf16(av[mg], bv[ng], acc[mg][ng], 0, 0, 0);
  }
  float* pb = part + ((int64_t)bh * 8 + s) * 4096;
  #pragma unroll
  for (int mg = 0; mg < 4; ++mg)
    #pragma unroll
    for (int ng = 0; ng < 4; ++ng)
      #pragma unroll
      for (int r = 0; r < 4; ++r)
        pb[(mg * 16 + ((lane >> 4) << 2) + r) * 64 + ng * 16 + arow] = acc[mg][ng][r];
}

// ---------------- K4b: sum partials, LayerNorm, M2T ------------
__global__ void k_ln(const float* __restrict__ part,
                     const float* __restrict__ gamma, const float* __restrict__ beta,
                     const unsigned short* __restrict__ P,
                     unsigned short* __restrict__ m2t) {
  __shared__ float spec[4096];
  __shared__ float red[8];
  __shared__ unsigned short Pl[64 * 256];
  const int bh = blockIdx.x, tid = threadIdx.x;
  const int h = bh & 7;
  const float* pb = part + (int64_t)bh * 8 * 4096;
  float lsum = 0.f, lsq = 0.f;
  for (int e = tid; e < 4096; e += 256) {
    float v = 0.f;
    #pragma unroll
    for (int s = 0; s < 8; ++s) v += pb[s * 4096 + e];
    spec[e] = v; lsum += v; lsq += v * v;
  }
  for (int e = tid; e < 64 * 256; e += 256) Pl[e] = P[(int64_t)h * 64 * 256 + e];
  #pragma unroll
  for (int s = 1; s < 64; s <<= 1) { lsum += __shfl_xor(lsum, s); lsq += __shfl_xor(lsq, s); }
  const int w = tid >> 6, lane = tid & 63;
  if (lane == 0) { red[w] = lsum; red[4 + w] = lsq; }
  __syncthreads();
  const float tsum = red[0] + red[1] + red[2] + red[3];
  const float tsq = red[4] + red[5] + red[6] + red[7];
  const float mu = tsum * (1.0f / 4096.0f);
  const float var = tsq * (1.0f / 4096.0f) - mu * mu;
  const float rs = rsqrtf(var + 1e-5f);
  for (int e = tid; e < 4096; e += 256) {
    spec[e] = (spec[e] - mu) * rs * gamma[e] + beta[e];
  }
  __syncthreads();
  const int co = tid;
  const int b_ = bh >> 3;
  unsigned short* dst = m2t + ((int64_t)(b_ * 256 + co)) * 512 + h * 64;
  float pr[64];
  #pragma unroll
  for (int i = 0; i < 64; ++i) pr[i] = bf2f(Pl[i * 256 + co]);
  for (int g0 = 0; g0 < 64; g0 += 8) {
    ushort8_t o;
    #pragma unroll
    for (int gi = 0; gi < 8; ++gi) {
      float a = 0.f;
      #pragma unroll
      for (int i = 0; i < 64; ++i) a += spec[(g0 + gi) * 64 + i] * pr[i];
      o[gi] = f2bf(a);
    }
    *(ushort8_t*)(dst + g0) = o;
  }
}

// ---------------- K5: final out GEMM ----------------
__launch_bounds__(256)
__global__ void k_out(const unsigned short* __restrict__ eigN,
                      const unsigned short* __restrict__ m2t,
                      const float* __restrict__ outb,
                      float* __restrict__ out, int b0) {
  const int swz = xcd_swz(blockIdx.x, gridDim.x);
  const int ct = swz & 1;
  const int mt = (swz >> 1) % 25;
  const int b  = swz / 50;
  const int w = threadIdx.x >> 6, lane = threadIdx.x & 63;
  const int wm = w >> 1, wn = w & 1;
  const int arow = lane & 15, koff = (lane >> 4) * 8;
  const int co0 = ct * 128 + wn * 64;
  const int n0 = mt * 128 + wm * 64;
  f32x4 acc[4][4] = {};
  const unsigned short* ebase = eigN + (int64_t)b * NH * NPAD * 64;
  const unsigned short* mbase = m2t + (int64_t)b * 256 * 512;
  for (int ks = 0; ks < 16; ++ks) {
    const int hh = ks >> 1;
    const int g0 = (ks & 1) * 32 + koff;
    bf16x8 av[4], bv[4];
    #pragma unroll
    for (int mg = 0; mg < 4; ++mg) {
      int n = n0 + mg * 16 + arow;
      if (n > NPAD - 1) n = NPAD - 1;
      av[mg] = *(const bf16x8*)(ebase + ((int64_t)hh * NPAD + n) * 64 + g0);
    }
    #pragma unroll
    for (int ng = 0; ng < 4; ++ng)
      bv[ng] = *(const bf16x8*)(mbase + (int64_t)(co0 + ng * 16 + arow) * 512 + ks * 32 + koff);
    #pragma unroll
    for (int mg = 0; mg < 4; ++mg)
      #pragma unroll
      for (int ng = 0; ng < 4; ++ng)
        acc[mg][ng] = __builtin_amdgcn_mfma_f32_16x16x32_bf16(av[mg], bv[ng], acc[mg][ng], 0, 0, 0);
  }
  #pragma unroll
  for (int mg = 0; mg < 4; ++mg) {
    const int nr = n0 + mg * 16 + ((lane >> 4) << 2);
    #pragma unroll
    for (int ng = 0; ng < 4; ++ng) {
      const int co = co0 + ng * 16 + arow;
      const float bv = outb[co];
      #pragma unroll
      for (int r = 0; r < 4; ++r) {
        if (nr + r < NN)
          out[((int64_t)(b0 + b) * NN + nr + r) * 256 + co] = acc[mg][ng][r] + bv;
      }
    }
  }
}

extern "C" void kernel_launch(void* const* d_in, const int* in_sizes, int n_in,
                              void* d_out, int out_size, void* d_ws, size_t ws_size,
                              hipStream_t stream) {
  const float* x     = (const float*)d_in[0];
  const float* fxw   = (const float*)d_in[1];
  const float* fxb   = (const float*)d_in[2];
  const float* xw    = (const float*)d_in[3];
  const float* xb    = (const float*)d_in[4];
  const float* gw    = (const float*)d_in[5];
  const float* gb    = (const float*)d_in[6];
  const float* temp  = (const float*)d_in[7];
  const float* gamma = (const float*)d_in[8];
  const float* beta  = (const float*)d_in[9];
  const float* mlp   = (const float*)d_in[10];
  const float* outw  = (const float*)d_in[11];
  const float* outb  = (const float*)d_in[12];
  const float* inver = (const float*)d_in[13];
  float* out = (float*)d_out;
  char* ws = (char*)d_ws;
  (void)in_sizes; (void)n_in; (void)out_size;

  // allow 128 KB dynamic LDS for the conv kernel (idempotent, host-side)
  hipFuncSetAttribute(reinterpret_cast<const void*>(k_conv8),
                      hipFuncAttributeMaxDynamicSharedMemorySize, 131072);

  int CB = 1;
  {
    const int cands[6] = {32, 16, 8, 4, 2, 1};
    for (int i = 0; i < 6; ++i) {
      unsigned long long need = 4993024ull + (unsigned long long)cands[i] * 14847488ull;
      if (need <= (unsigned long long)ws_size) { CB = cands[i]; break; }
    }
  }

  unsigned short* Wb   = (unsigned short*)(ws + 0);
  float*          bias = (float*)(ws + 4718592);
  unsigned short* gwb  = (unsigned short*)(ws + 4722688);
  unsigned short* P    = (unsigned short*)(ws + 4730880);
  const size_t F0      = 4993024;
  const size_t szXpad  = (size_t)CB * 1740288;
  const size_t szM2t   = (size_t)CB * 262144;
  const size_t szBig   = (size_t)CB * 3211264;
  unsigned short* xpad = (unsigned short*)(ws + F0);
  float*          part = (float*)(ws + F0);
  unsigned short* m2t  = (unsigned short*)(ws + F0 + szXpad);
  unsigned short* fxT  = (unsigned short*)(ws + F0 + szXpad + szM2t);
  unsigned short* xmid = (unsigned short*)(ws + F0 + szXpad + szM2t + szBig);
  unsigned short* eigT = (unsigned short*)(ws + F0 + szXpad + szM2t + 2 * szBig);
  unsigned short* eigN = (unsigned short*)(ws + F0 + szXpad + szM2t + 3 * szBig);

  k_wpack<<<dim3(9216), dim3(256), 0, stream>>>(fxw, xw, fxb, xb, gw, Wb, bias, gwb);
  k_pprep<<<dim3(512), dim3(256), 0, stream>>>(mlp, outw, P);

  for (int b0 = 0; b0 < BB; b0 += CB) {
    k_pad<<<dim3(WP, HP, CB), dim3(64), 0, stream>>>(x, xpad, b0);
    k_padzero<<<dim3(CB * 10), dim3(256), 0, stream>>>(fxT, xmid, CB);
    k_conv8<<<dim3(52 * CB), dim3(512), 131072, stream>>>(xpad, Wb, bias, fxT, xmid);
    k_eig<<<dim3(49, 8, CB), dim3(256), 0, stream>>>(xmid, gwb, gb, temp, inver, eigT, eigN);
    k_spec<<<dim3(2, 8, CB), dim3(256), 0, stream>>>(eigT, fxT, part);
    k_ln<<<dim3(CB * 8), dim3(256), 0, stream>>>(part, gamma, beta, P, m2t);
    k_out<<<dim3(50 * CB), dim3(256), 0, stream>>>(eigN, m2t, outb, out, b0);
  }
}

// Round 5
// 930.061 us; speedup vs baseline: 1.3330x; 1.2337x over previous
//
#include <hip/hip_runtime.h>
#include <hip/hip_bf16.h>
#include <stdint.h>

#define HH 101
#define WW 31
#define NN 3131
#define NPAD 3136
#define BB 32
#define NH 8
#define CDIM 256
#define GG 64
#define HP 103
#define WP 33

typedef __attribute__((ext_vector_type(8))) short bf16x8;
typedef __attribute__((ext_vector_type(4))) float f32x4;
typedef __attribute__((ext_vector_type(4))) unsigned short ushort4_t;
typedef __attribute__((ext_vector_type(8))) unsigned short ushort8_t;
typedef __attribute__((ext_vector_type(4))) float float4_t;

static __device__ __forceinline__ unsigned short f2bf(float f) {
  union { float f; uint32_t u; } v; v.f = f;
  uint32_t u = v.u;
  return (unsigned short)((u + 0x7fffu + ((u >> 16) & 1u)) >> 16);
}
static __device__ __forceinline__ float bf2f(unsigned short h) {
  union { uint32_t u; float f; } v; v.u = ((uint32_t)h) << 16;
  return v.f;
}
static __device__ __forceinline__ void gload_lds16(const void* g, void* l) {
  __builtin_amdgcn_global_load_lds((const __attribute__((address_space(1))) void*)g,
                                   (__attribute__((address_space(3))) void*)l, 16, 0, 0);
}
// m204 bijective XCD swizzle
static __device__ __forceinline__ int xcd_swz(int bid, int nwg) {
  int q = nwg >> 3, r = nwg & 7;
  int xcd = bid & 7, pos = bid >> 3;
  int base = (xcd < r) ? xcd * (q + 1) : r * (q + 1) + (xcd - r) * q;
  return base + pos;
}

// ---------------- K0: pad + cast x -> bf16 (CB, HP, WP, C) ----------------
__global__ void k_pad(const float* __restrict__ x, unsigned short* __restrict__ xpad, int b0) {
  const int xx = blockIdx.x, yy = blockIdx.y, b = blockIdx.z;
  const int t = threadIdx.x;
  ushort4_t o; o.x = 0; o.y = 0; o.z = 0; o.w = 0;
  if (yy >= 1 && yy <= HH && xx >= 1 && xx <= WW) {
    const int n = (yy - 1) * WW + (xx - 1);
    const float4_t v = *(const float4_t*)(x + (((int64_t)(b0 + b) * NN + n) * CDIM + t * 4));
    o.x = f2bf(v.x); o.y = f2bf(v.y); o.z = f2bf(v.z); o.w = f2bf(v.w);
  }
  *(ushort4_t*)(xpad + (((int64_t)b * HP + yy) * WP + xx) * CDIM + t * 4) = o;
}

// ---------------- K1: pack conv weights, bias, gate_w ----------------
__global__ void k_wpack(const float* __restrict__ fxw, const float* __restrict__ xw,
                        const float* __restrict__ fxb, const float* __restrict__ xb,
                        const float* __restrict__ gw,
                        unsigned short* __restrict__ Wb, float* __restrict__ bias,
                        unsigned short* __restrict__ gwb) {
  int tid = blockIdx.x * blockDim.x + threadIdx.x;
  const int total = 9 * 1024 * 256;
  if (tid < total) {
    int cin = tid & 255; int rest = tid >> 8; int co = rest & 1023; int t = rest >> 10;
    float v = (co < 512) ? fxw[(int64_t)co * 2304 + cin * 9 + t]
                         : xw[(int64_t)(co - 512) * 2304 + cin * 9 + t];
    Wb[tid] = f2bf(v);
  }
  if (tid < 1024) bias[tid] = (tid < 512) ? fxb[tid] : xb[tid - 512];
  if (tid < 4096) gwb[tid] = f2bf(gw[tid]);
}

// ---------------- K1b: Pt[h][co][i] = sum_c mlp_w[i][c] * out_w[co][h*64+c] (bf16) --------
__global__ void k_pprep(const float* __restrict__ mlp, const float* __restrict__ outw,
                        unsigned short* __restrict__ Pt) {
  int h = blockIdx.x >> 6, i = blockIdx.x & 63, co = threadIdx.x;
  float a = 0.f;
  for (int c = 0; c < 64; ++c) a += mlp[i * 64 + c] * outw[(int64_t)co * 512 + h * 64 + c];
  Pt[((int64_t)h * 256 + co) * 64 + i] = f2bf(a);
}

// ---------------- K1c: zero pad tails of fxT (cols) and xmid (rows) ----------
__global__ void k_padzero(unsigned short* __restrict__ fxT, unsigned short* __restrict__ xmid,
                          int CB) {
  int tid = blockIdx.x * blockDim.x + threadIdx.x;
  if (tid >= CB * 2560) return;
  {
    int j = tid % 5; int rc = tid / 5;
    fxT[(int64_t)rc * NPAD + NN + j] = 0;
  }
  {
    int d = tid & 63; int rest = tid >> 6;
    int j = rest % 5; int bh = rest / 5;
    xmid[((int64_t)bh * NPAD + NN + j) * 64 + d] = 0;
  }
}

// ---------------- K2: 256x256 implicit-GEMM conv, 1 barrier/K-tile, free-run ----------------
// 8 waves (2Mx4N), BK=32, 4 LDS slots (128KB), prefetch depth 2, vmcnt(4) counted
// (never 0 in loop). NO mid-tile barrier: waves skew so ds_read (LDS pipe) overlaps
// MFMA (matrix pipes) across waves.
static __device__ __forceinline__ void stage_a8(const unsigned short* aS0, const unsigned short* aS1,
                                                unsigned short* lds, int s, int wid, int kt) {
  const int t = kt >> 3;
  const int dy = (t >= 6) + (t >= 3);
  const int dx = t - dy * 3;
  const int aoff = (dy * WP + dx) * CDIM + (kt & 7) * 32;
  gload_lds16(aS0 + aoff, lds + s * 16384 + wid * 512);
  gload_lds16(aS1 + aoff, lds + s * 16384 + 4096 + wid * 512);
}
static __device__ __forceinline__ void stage_b8(const unsigned short* bS0, const unsigned short* bS1,
                                                unsigned short* lds, int s, int wid, int kt) {
  const int t = kt >> 3;
  const int boff = t * (1024 * CDIM) + (kt & 7) * 32;
  gload_lds16(bS0 + boff, lds + s * 16384 + 8192 + wid * 512);
  gload_lds16(bS1 + boff, lds + s * 16384 + 8192 + 4096 + wid * 512);
}

__launch_bounds__(512, 2)
__global__ void k_conv8(const unsigned short* __restrict__ xpad,
                        const unsigned short* __restrict__ Wb,
                        const float* __restrict__ bias,
                        unsigned short* __restrict__ fxT,
                        unsigned short* __restrict__ xmid) {
  extern __shared__ unsigned short lds[];   // 4 slots x 16384 elems = 128 KB
  const int swz = xcd_swz(blockIdx.x, gridDim.x);
  const int r   = swz % 52;
  const int b   = swz / 52;
  const int bx  = r & 3;
  const int mt  = r >> 2;
  const int tid = threadIdx.x, wid = tid >> 6, lane = tid & 63;
  const int wm = wid >> 2, wn = wid & 3;
  const int arow = lane & 15, col16 = lane >> 4;
  const int n00 = mt * 256, co00 = bx * 256;

  const int srow = wid * 16 + (lane >> 2);
  const int tc   = ((lane & 3) ^ ((srow ^ (srow >> 2)) & 3)) * 8;
  int na0 = n00 + srow;        if (na0 >= NN) na0 = NN - 1;
  int na1 = n00 + srow + 128;  if (na1 >= NN) na1 = NN - 1;
  const int y0 = na0 / WW, x0v = na0 % WW;
  const int y1 = na1 / WW, x1v = na1 % WW;
  const unsigned short* aS0 = xpad + ((int64_t)(b * HP + y0) * WP + x0v) * CDIM + tc;
  const unsigned short* aS1 = xpad + ((int64_t)(b * HP + y1) * WP + x1v) * CDIM + tc;
  const unsigned short* bS0 = Wb + (int64_t)(co00 + srow) * CDIM + tc;
  const unsigned short* bS1 = Wb + (int64_t)(co00 + srow + 128) * CDIM + tc;

  const int rdcol = (col16 ^ ((arow ^ (arow >> 2)) & 3)) * 8;

  f32x4 acc[8][4] = {};

  stage_a8(aS0, aS1, lds, 0, wid, 0); stage_b8(bS0, bS1, lds, 0, wid, 0);
  stage_a8(aS0, aS1, lds, 1, wid, 1); stage_b8(bS0, bS1, lds, 1, wid, 1);

  for (int kt = 0; kt < 72; ++kt) {
    const int s = kt & 3;
    const unsigned short* sA = lds + s * 16384;
    const unsigned short* sB = sA + 8192;
    const int s2  = (kt + 2) & 3;
    const int kt2 = (kt + 2 > 71) ? 71 : kt + 2;

    // K-tile entry: drain this tile's 4 stages (issued during kt-1), rendezvous.
    asm volatile("s_waitcnt vmcnt(4)" ::: "memory");
    __builtin_amdgcn_s_barrier();
    asm volatile("" ::: "memory");
    __builtin_amdgcn_sched_barrier(0);

    // issue next-next tile's stages first (overlap with reads+MFMA)
    stage_a8(aS0, aS1, lds, s2, wid, kt2);
    stage_b8(bS0, bS1, lds, s2, wid, kt2);

    bf16x8 av[8], bv[4];
    #pragma unroll
    for (int mf = 0; mf < 8; ++mf)
      av[mf] = *(const bf16x8*)(sA + (wm * 128 + mf * 16 + arow) * 32 + rdcol);
    #pragma unroll
    for (int nf = 0; nf < 4; ++nf)
      bv[nf] = *(const bf16x8*)(sB + (wn * 64 + nf * 16 + arow) * 32 + rdcol);
    __builtin_amdgcn_s_setprio(1);
    #pragma unroll
    for (int mf = 0; mf < 8; ++mf)
      #pragma unroll
      for (int nf = 0; nf < 4; ++nf)
        acc[mf][nf] = __builtin_amdgcn_mfma_f32_16x16x32_bf16(av[mf], bv[nf], acc[mf][nf], 0, 0, 0);
    __builtin_amdgcn_s_setprio(0);
  }

  asm volatile("s_waitcnt vmcnt(0)" ::: "memory");

  const int rowoff = col16 * 4;
  #pragma unroll
  for (int mf = 0; mf < 8; ++mf) {
    const int nr = n00 + wm * 128 + mf * 16 + rowoff;
    #pragma unroll
    for (int nf = 0; nf < 4; ++nf) {
      const int co = co00 + wn * 64 + nf * 16 + arow;
      const float bvs = bias[co];
      const float v0 = acc[mf][nf][0] + bvs;
      const float v1 = acc[mf][nf][1] + bvs;
      const float v2 = acc[mf][nf][2] + bvs;
      const float v3 = acc[mf][nf][3] + bvs;
      if (bx < 2) {
        const int h = co >> 6, c = co & 63;
        unsigned short* dst = fxT + ((int64_t)((b * NH + h) * 64 + c)) * NPAD + nr;
        if (nr + 3 < NN) {
          ushort4_t o; o.x = f2bf(v0); o.y = f2bf(v1); o.z = f2bf(v2); o.w = f2bf(v3);
          *(ushort4_t*)dst = o;
        } else {
          if (nr + 0 < NN) dst[0] = f2bf(v0);
          if (nr + 1 < NN) dst[1] = f2bf(v1);
          if (nr + 2 < NN) dst[2] = f2bf(v2);
          if (nr + 3 < NN) dst[3] = f2bf(v3);
        }
      } else {
        const int h = (co >> 6) & 7, d = co & 63;
        unsigned short* dst = xmid + ((int64_t)(b * NH + h) * NPAD + nr) * 64 + d;
        if (nr + 0 < NN) dst[0] = f2bf(v0);
        if (nr + 1 < NN) dst[64] = f2bf(v1);
        if (nr + 2 < NN) dst[128] = f2bf(v2);
        if (nr + 3 < NN) dst[192] = f2bf(v3);
      }
    }
  }
}

// ---------------- K3: logits MFMA + softmax + eigens; LDS-staged coalesced stores -------
__global__ void k_eig(const unsigned short* __restrict__ xmid,
                      const unsigned short* __restrict__ gwb,
                      const float* __restrict__ gateb,
                      const float* __restrict__ temperature,
                      const float* __restrict__ inver,
                      unsigned short* __restrict__ eigT,
                      unsigned short* __restrict__ eigN) {
  __shared__ unsigned short egN[64 * 72];
  __shared__ unsigned short egT[64 * 72];
  const int nt = blockIdx.x, h = blockIdx.y, b = blockIdx.z;
  const int tid = threadIdx.x;
  const int w = tid >> 6, lane = tid & 63;
  const int n0 = nt * 64 + w * 16;
  const int bh = b * NH + h;
  float tv = temperature[h];
  tv = fminf(fmaxf(tv, 0.1f), 5.0f);
  const float itemp = 1.0f / tv;
  const int arow = lane & 15;
  const int koff = (lane >> 4) * 8;
  const unsigned short* aptr = xmid + ((int64_t)bh * NPAD + (n0 + arow)) * 64 + koff;
  bf16x8 a0 = *(const bf16x8*)(aptr);
  bf16x8 a1 = *(const bf16x8*)(aptr + 32);
  f32x4 acc[4] = {};
  #pragma unroll
  for (int ng = 0; ng < 4; ++ng) {
    const unsigned short* bptr = gwb + (ng * 16 + arow) * 64 + koff;
    bf16x8 b0 = *(const bf16x8*)(bptr);
    bf16x8 b1 = *(const bf16x8*)(bptr + 32);
    acc[ng] = __builtin_amdgcn_mfma_f32_16x16x32_bf16(a0, b0, acc[ng], 0, 0, 0);
    acc[ng] = __builtin_amdgcn_mfma_f32_16x16x32_bf16(a1, b1, acc[ng], 0, 0, 0);
  }
  #pragma unroll
  for (int r = 0; r < 4; ++r) {
    const int nl = w * 16 + ((lane >> 4) << 2) + r;
    const int n = nt * 64 + nl;
    float vals[4];
    #pragma unroll
    for (int ng = 0; ng < 4; ++ng) vals[ng] = (acc[ng][r] + gateb[ng * 16 + arow]) * itemp;
    float mx = fmaxf(fmaxf(vals[0], vals[1]), fmaxf(vals[2], vals[3]));
    #pragma unroll
    for (int s = 1; s < 16; s <<= 1) mx = fmaxf(mx, __shfl_xor(mx, s));
    float ex[4]; float sum = 0.f;
    #pragma unroll
    for (int ng = 0; ng < 4; ++ng) { ex[ng] = __expf(vals[ng] - mx); sum += ex[ng]; }
    #pragma unroll
    for (int s = 1; s < 16; s <<= 1) sum += __shfl_xor(sum, s);
    const float inv = 1.0f / sum;
    const bool valid = (n < NN);
    #pragma unroll
    for (int ng = 0; ng < 4; ++ng) {
      const int g = ng * 16 + arow;
      float iv = valid ? inver[(int64_t)n * GG + g] : 0.f;
      unsigned short u = valid ? f2bf(ex[ng] * inv * iv) : (unsigned short)0;
      egN[nl * 72 + g] = u;
      egT[g * 72 + nl] = u;
    }
  }
  __syncthreads();
  const int row = tid >> 2, c0 = (tid & 3) << 4;
  {
    ushort8_t v0 = *(ushort8_t*)&egN[row * 72 + c0];
    ushort8_t v1 = *(ushort8_t*)&egN[row * 72 + c0 + 8];
    unsigned short* dst = eigN + ((int64_t)bh * NPAD + nt * 64 + row) * 64 + c0;
    *(ushort8_t*)dst = v0; *(ushort8_t*)(dst + 8) = v1;
  }
  {
    ushort8_t v0 = *(ushort8_t*)&egT[row * 72 + c0];
    ushort8_t v1 = *(ushort8_t*)&egT[row * 72 + c0 + 8];
    unsigned short* dst = eigT + ((int64_t)(bh * 64 + row)) * NPAD + nt * 64 + c0;
    *(ushort8_t*)dst = v0; *(ushort8_t*)(dst + 8) = v1;
  }
}

// ---------------- K4: fused spec-GEMM + LayerNorm + (LN(spec) @ P_h) -> m2t ------------
// One block per (b,h): 4 waves k-split the N=3136 reduction, partials via LDS,
// joint LN over (g,c), then MFMA x Pt (spec tile XOR-swizzled in LDS), coalesced store.
__launch_bounds__(256, 1)
__global__ void k_specln(const unsigned short* __restrict__ eigT,
                         const unsigned short* __restrict__ fxT,
                         const float* __restrict__ gamma, const float* __restrict__ beta,
                         const unsigned short* __restrict__ Pt,
                         unsigned short* __restrict__ m2t) {
  extern __shared__ char sm[];
  float* sacc = (float*)sm;                                   // [4][64][65] f32 = 66560 B
  unsigned short* specb = (unsigned short*)(sm + 66560);      // [64][64] bf16 swz = 8192 B
  float* red = (float*)(sm + 74752);                          // 8 f32
  unsigned short* mstrip = (unsigned short*)(sm + 74784);     // [4][64][72] u16 = 36864 B
  const int bhl = blockIdx.x;
  const int h = bhl & 7, bl = bhl >> 3;
  const int tid = threadIdx.x, w = tid >> 6, lane = tid & 63;
  const int arow = lane & 15, col16 = lane >> 4;
  const int koff = col16 * 8;
  const unsigned short* eb = eigT + (int64_t)bhl * 64 * NPAD;
  const unsigned short* fb = fxT + (int64_t)bhl * 64 * NPAD;

  // phase 1: partial spec GEMM over this wave's k-slice
  const int ks0 = (98 * w) >> 2, ks1 = (98 * (w + 1)) >> 2;
  f32x4 acc[4][4] = {};
  for (int ks = ks0; ks < ks1; ++ks) {
    const int k0 = ks * 32 + koff;
    bf16x8 av[4], bv[4];
    #pragma unroll
    for (int mg = 0; mg < 4; ++mg) av[mg] = *(const bf16x8*)(eb + (int64_t)(mg * 16 + arow) * NPAD + k0);
    #pragma unroll
    for (int ng = 0; ng < 4; ++ng) bv[ng] = *(const bf16x8*)(fb + (int64_t)(ng * 16 + arow) * NPAD + k0);
    #pragma unroll
    for (int mg = 0; mg < 4; ++mg)
      #pragma unroll
      for (int ng = 0; ng < 4; ++ng)
        acc[mg][ng] = __builtin_amdgcn_mfma_f32_16x16x32_bf16(av[mg], bv[ng], acc[mg][ng], 0, 0, 0);
  }
  float* pw = sacc + w * (64 * 65);
  #pragma unroll
  for (int mg = 0; mg < 4; ++mg)
    #pragma unroll
    for (int ng = 0; ng < 4; ++ng)
      #pragma unroll
      for (int r = 0; r < 4; ++r)
        pw[(mg * 16 + col16 * 4 + r) * 65 + ng * 16 + arow] = acc[mg][ng][r];
  __syncthreads();

  // phase 2: reduce 4 slices + LN stats
  float vloc[16];
  float lsum = 0.f, lsq = 0.f;
  #pragma unroll
  for (int idx = 0; idx < 16; ++idx) {
    const int e = tid + idx * 256;
    const int g = e >> 6, c = e & 63;
    float v = sacc[g * 65 + c] + sacc[4160 + g * 65 + c] +
              sacc[8320 + g * 65 + c] + sacc[12480 + g * 65 + c];
    vloc[idx] = v; lsum += v; lsq += v * v;
  }
  #pragma unroll
  for (int s = 1; s < 64; s <<= 1) { lsum += __shfl_xor(lsum, s); lsq += __shfl_xor(lsq, s); }
  if (lane == 0) { red[w] = lsum; red[4 + w] = lsq; }
  __syncthreads();
  const float tsum = red[0] + red[1] + red[2] + red[3];
  const float tsq = red[4] + red[5] + red[6] + red[7];
  const float mu = tsum * (1.0f / 4096.0f);
  const float var = tsq * (1.0f / 4096.0f) - mu * mu;
  const float rs = rsqrtf(var + 1e-5f);
  // write normalized spec as bf16, XOR-swizzled 16B units: i8' = i8 ^ (g&7)
  #pragma unroll
  for (int idx = 0; idx < 16; ++idx) {
    const int e = tid + idx * 256;
    const int g = e >> 6, c = e & 63;
    float sv = (vloc[idx] - mu) * rs * gamma[e] + beta[e];
    specb[g * 64 + ((((c >> 3) ^ (g & 7))) << 3) + (c & 7)] = f2bf(sv);
  }
  __syncthreads();

  // phase 3: M2[g][co] = sum_i spec[g][i] * Pt[h][co][i];  wave w -> co strip w*64
  f32x4 a2[4][4] = {};
  const unsigned short* pth = Pt + ((int64_t)h * 256 + w * 64) * 64;
  #pragma unroll
  for (int kk = 0; kk < 2; ++kk) {
    const int i0 = kk * 32 + koff;
    const int i8 = (i0 >> 3);
    bf16x8 av2[4], bv2[4];
    #pragma unroll
    for (int mg = 0; mg < 4; ++mg) {
      const int g = mg * 16 + arow;
      av2[mg] = *(const bf16x8*)(specb + g * 64 + ((i8 ^ (g & 7)) << 3));
    }
    #pragma unroll
    for (int ng = 0; ng < 4; ++ng)
      bv2[ng] = *(const bf16x8*)(pth + (ng * 16 + arow) * 64 + i0);
    #pragma unroll
    for (int mg = 0; mg < 4; ++mg)
      #pragma unroll
      for (int ng = 0; ng < 4; ++ng)
        a2[mg][ng] = __builtin_amdgcn_mfma_f32_16x16x32_bf16(av2[mg], bv2[ng], a2[mg][ng], 0, 0, 0);
  }
  // C: row = g (mg*16+col16*4+r), col = co_local (ng*16+arow); bounce via LDS strip
  unsigned short* ms = mstrip + w * (64 * 72);
  #pragma unroll
  for (int mg = 0; mg < 4; ++mg)
    #pragma unroll
    for (int ng = 0; ng < 4; ++ng)
      #pragma unroll
      for (int r = 0; r < 4; ++r)
        ms[(ng * 16 + arow) * 72 + mg * 16 + col16 * 4 + r] = f2bf(a2[mg][ng][r]);
  __syncthreads();
  // coalesced m2t store: m2t[(bl*256 + w*64 + co)*512 + h*64 + g]
  #pragma unroll
  for (int e0 = 0; e0 < 8; ++e0) {
    const int e = lane + e0 * 64;
    const int row = e >> 3, g8 = e & 7;
    ushort8_t v = *(ushort8_t*)&ms[row * 72 + g8 * 8];
    *(ushort8_t*)(m2t + ((int64_t)(bl * 256 + w * 64 + row)) * 512 + h * 64 + g8 * 8) = v;
  }
}

// ---------------- K5: final out GEMM ----------------
__launch_bounds__(256)
__global__ void k_out(const unsigned short* __restrict__ eigN,
                      const unsigned short* __restrict__ m2t,
                      const float* __restrict__ outb,
                      float* __restrict__ out, int b0) {
  const int swz = xcd_swz(blockIdx.x, gridDim.x);
  const int ct = swz & 1;
  const int mt = (swz >> 1) % 25;
  const int b  = swz / 50;
  const int w = threadIdx.x >> 6, lane = threadIdx.x & 63;
  const int wm = w >> 1, wn = w & 1;
  const int arow = lane & 15, koff = (lane >> 4) * 8;
  const int co0 = ct * 128 + wn * 64;
  const int n0 = mt * 128 + wm * 64;
  f32x4 acc[4][4] = {};
  const unsigned short* ebase = eigN + (int64_t)b * NH * NPAD * 64;
  const unsigned short* mbase = m2t + (int64_t)b * 256 * 512;
  for (int ks = 0; ks < 16; ++ks) {
    const int hh = ks >> 1;
    const int g0 = (ks & 1) * 32 + koff;
    bf16x8 av[4], bv[4];
    #pragma unroll
    for (int mg = 0; mg < 4; ++mg) {
      int n = n0 + mg * 16 + arow;
      if (n > NPAD - 1) n = NPAD - 1;
      av[mg] = *(const bf16x8*)(ebase + ((int64_t)hh * NPAD + n) * 64 + g0);
    }
    #pragma unroll
    for (int ng = 0; ng < 4; ++ng)
      bv[ng] = *(const bf16x8*)(mbase + (int64_t)(co0 + ng * 16 + arow) * 512 + ks * 32 + koff);
    #pragma unroll
    for (int mg = 0; mg < 4; ++mg)
      #pragma unroll
      for (int ng = 0; ng < 4; ++ng)
        acc[mg][ng] = __builtin_amdgcn_mfma_f32_16x16x32_bf16(av[mg], bv[ng], acc[mg][ng], 0, 0, 0);
  }
  #pragma unroll
  for (int mg = 0; mg < 4; ++mg) {
    const int nr = n0 + mg * 16 + ((lane >> 4) << 2);
    #pragma unroll
    for (int ng = 0; ng < 4; ++ng) {
      const int co = co0 + ng * 16 + arow;
      const float bv = outb[co];
      #pragma unroll
      for (int r = 0; r < 4; ++r) {
        if (nr + r < NN)
          out[((int64_t)(b0 + b) * NN + nr + r) * 256 + co] = acc[mg][ng][r] + bv;
      }
    }
  }
}

extern "C" void kernel_launch(void* const* d_in, const int* in_sizes, int n_in,
                              void* d_out, int out_size, void* d_ws, size_t ws_size,
                              hipStream_t stream) {
  const float* x     = (const float*)d_in[0];
  const float* fxw   = (const float*)d_in[1];
  const float* fxb   = (const float*)d_in[2];
  const float* xw    = (const float*)d_in[3];
  const float* xb    = (const float*)d_in[4];
  const float* gw    = (const float*)d_in[5];
  const float* gb    = (const float*)d_in[6];
  const float* temp  = (const float*)d_in[7];
  const float* gamma = (const float*)d_in[8];
  const float* beta  = (const float*)d_in[9];
  const float* mlp   = (const float*)d_in[10];
  const float* outw  = (const float*)d_in[11];
  const float* outb  = (const float*)d_in[12];
  const float* inver = (const float*)d_in[13];
  float* out = (float*)d_out;
  char* ws = (char*)d_ws;
  (void)in_sizes; (void)n_in; (void)out_size;

  hipFuncSetAttribute(reinterpret_cast<const void*>(k_conv8),
                      hipFuncAttributeMaxDynamicSharedMemorySize, 131072);
  hipFuncSetAttribute(reinterpret_cast<const void*>(k_specln),
                      hipFuncAttributeMaxDynamicSharedMemorySize, 131072);

  int CB = 1;
  {
    const int cands[6] = {32, 16, 8, 4, 2, 1};
    for (int i = 0; i < 6; ++i) {
      unsigned long long need = 4993024ull + (unsigned long long)cands[i] * 14847488ull;
      if (need <= (unsigned long long)ws_size) { CB = cands[i]; break; }
    }
  }

  unsigned short* Wb   = (unsigned short*)(ws + 0);
  float*          bias = (float*)(ws + 4718592);
  unsigned short* gwb  = (unsigned short*)(ws + 4722688);
  unsigned short* Pt   = (unsigned short*)(ws + 4730880);
  const size_t F0      = 4993024;
  const size_t szXpad  = (size_t)CB * 1740288;
  const size_t szM2t   = (size_t)CB * 262144;
  const size_t szBig   = (size_t)CB * 3211264;
  unsigned short* xpad = (unsigned short*)(ws + F0);
  unsigned short* m2t  = (unsigned short*)(ws + F0 + szXpad);
  unsigned short* fxT  = (unsigned short*)(ws + F0 + szXpad + szM2t);
  unsigned short* xmid = (unsigned short*)(ws + F0 + szXpad + szM2t + szBig);
  unsigned short* eigT = (unsigned short*)(ws + F0 + szXpad + szM2t + 2 * szBig);
  unsigned short* eigN = (unsigned short*)(ws + F0 + szXpad + szM2t + 3 * szBig);

  k_wpack<<<dim3(9216), dim3(256), 0, stream>>>(fxw, xw, fxb, xb, gw, Wb, bias, gwb);
  k_pprep<<<dim3(512), dim3(256), 0, stream>>>(mlp, outw, Pt);

  for (int b0 = 0; b0 < BB; b0 += CB) {
    k_pad<<<dim3(WP, HP, CB), dim3(64), 0, stream>>>(x, xpad, b0);
    k_padzero<<<dim3(CB * 10), dim3(256), 0, stream>>>(fxT, xmid, CB);
    k_conv8<<<dim3(52 * CB), dim3(512), 131072, stream>>>(xpad, Wb, bias, fxT, xmid);
    k_eig<<<dim3(49, 8, CB), dim3(256), 0, stream>>>(xmid, gwb, gb, temp, inver, eigT, eigN);
    k_specln<<<dim3(CB * 8), dim3(256), 111648, stream>>>(eigT, fxT, gamma, beta, Pt, m2t);
    k_out<<<dim3(50 * CB), dim3(256), 0, stream>>>(eigN, m2t, outb, out, b0);
  }
}

// Round 6
// 905.562 us; speedup vs baseline: 1.3690x; 1.0271x over previous
//
#include <hip/hip_runtime.h>
#include <hip/hip_bf16.h>
#include <stdint.h>

#define HH 101
#define WW 31
#define NN 3131
#define NPAD 3136
#define BB 32
#define NH 8
#define CDIM 256
#define GG 64
#define HP 103
#define WP 33

typedef __attribute__((ext_vector_type(8))) short bf16x8;
typedef __attribute__((ext_vector_type(4))) float f32x4;
typedef __attribute__((ext_vector_type(4))) unsigned short ushort4_t;
typedef __attribute__((ext_vector_type(8))) unsigned short ushort8_t;
typedef __attribute__((ext_vector_type(4))) float float4_t;

static __device__ __forceinline__ unsigned short f2bf(float f) {
  union { float f; uint32_t u; } v; v.f = f;
  uint32_t u = v.u;
  return (unsigned short)((u + 0x7fffu + ((u >> 16) & 1u)) >> 16);
}
static __device__ __forceinline__ float bf2f(unsigned short h) {
  union { uint32_t u; float f; } v; v.u = ((uint32_t)h) << 16;
  return v.f;
}
static __device__ __forceinline__ void gload_lds16(const void* g, void* l) {
  __builtin_amdgcn_global_load_lds((const __attribute__((address_space(1))) void*)g,
                                   (__attribute__((address_space(3))) void*)l, 16, 0, 0);
}
// m204 bijective XCD swizzle
static __device__ __forceinline__ int xcd_swz(int bid, int nwg) {
  int q = nwg >> 3, r = nwg & 7;
  int xcd = bid & 7, pos = bid >> 3;
  int base = (xcd < r) ? xcd * (q + 1) : r * (q + 1) + (xcd - r) * q;
  return base + pos;
}

// ---------------- K0: pad + cast x -> bf16 (CB, HP, WP, C) ----------------
__global__ void k_pad(const float* __restrict__ x, unsigned short* __restrict__ xpad, int b0) {
  const int xx = blockIdx.x, yy = blockIdx.y, b = blockIdx.z;
  const int t = threadIdx.x;
  ushort4_t o; o.x = 0; o.y = 0; o.z = 0; o.w = 0;
  if (yy >= 1 && yy <= HH && xx >= 1 && xx <= WW) {
    const int n = (yy - 1) * WW + (xx - 1);
    const float4_t v = *(const float4_t*)(x + (((int64_t)(b0 + b) * NN + n) * CDIM + t * 4));
    o.x = f2bf(v.x); o.y = f2bf(v.y); o.z = f2bf(v.z); o.w = f2bf(v.w);
  }
  *(ushort4_t*)(xpad + (((int64_t)b * HP + yy) * WP + xx) * CDIM + t * 4) = o;
}

// ---------------- K1: pack conv weights, bias, gate_w ----------------
__global__ void k_wpack(const float* __restrict__ fxw, const float* __restrict__ xw,
                        const float* __restrict__ fxb, const float* __restrict__ xb,
                        const float* __restrict__ gw,
                        unsigned short* __restrict__ Wb, float* __restrict__ bias,
                        unsigned short* __restrict__ gwb) {
  int tid = blockIdx.x * blockDim.x + threadIdx.x;
  const int total = 9 * 1024 * 256;
  if (tid < total) {
    int cin = tid & 255; int rest = tid >> 8; int co = rest & 1023; int t = rest >> 10;
    float v = (co < 512) ? fxw[(int64_t)co * 2304 + cin * 9 + t]
                         : xw[(int64_t)(co - 512) * 2304 + cin * 9 + t];
    Wb[tid] = f2bf(v);
  }
  if (tid < 1024) bias[tid] = (tid < 512) ? fxb[tid] : xb[tid - 512];
  if (tid < 4096) gwb[tid] = f2bf(gw[tid]);
}

// ---------------- K1b: Pt[h][co][i] = sum_c mlp_w[i][c] * out_w[co][h*64+c] (bf16) --------
__global__ void k_pprep(const float* __restrict__ mlp, const float* __restrict__ outw,
                        unsigned short* __restrict__ Pt) {
  int h = blockIdx.x >> 6, i = blockIdx.x & 63, co = threadIdx.x;
  float a = 0.f;
  for (int c = 0; c < 64; ++c) a += mlp[i * 64 + c] * outw[(int64_t)co * 512 + h * 64 + c];
  Pt[((int64_t)h * 256 + co) * 64 + i] = f2bf(a);
}

// ---------------- K1c: zero pad tails of fxT (cols) and xmid (rows) ----------
__global__ void k_padzero(unsigned short* __restrict__ fxT, unsigned short* __restrict__ xmid,
                          int CB) {
  int tid = blockIdx.x * blockDim.x + threadIdx.x;
  if (tid >= CB * 2560) return;
  {
    int j = tid % 5; int rc = tid / 5;
    fxT[(int64_t)rc * NPAD + NN + j] = 0;
  }
  {
    int d = tid & 63; int rest = tid >> 6;
    int j = rest % 5; int bh = rest / 5;
    xmid[((int64_t)bh * NPAD + NN + j) * 64 + d] = 0;
  }
}

// ---------------- K2: 256x256 implicit-GEMM conv, m201-style 8-phase schedule -------------
// BK=64 K-steps (36). LDS: 2 buffers x (A[2][256][32] + B[2][256][32]) = 128KB.
// 4 chunks/K-step (A-k0, B-k0, A-k1, B-k1), each LDS-contiguous 16KB = 2 gload16/thread.
// 4 phases/K-step: {ds_read subtile | stage 1 chunk | vmcnt(4) @P2,P4 only | barrier |
//   lgkmcnt(0) | setprio(1) 16 MFMA setprio(0) | barrier}. Never vmcnt(0) in loop (T4).
// T2 swizzle: 16B-unit' = unit ^ ((row>>1)&3), inverse-applied on global source (rule 21).
__launch_bounds__(512, 2)
__global__ void k_conv8(const unsigned short* __restrict__ xpad,
                        const unsigned short* __restrict__ Wb,
                        const float* __restrict__ bias,
                        unsigned short* __restrict__ fxT,
                        unsigned short* __restrict__ xmid) {
  extern __shared__ unsigned short lds[];   // 2 x 32768 elems
  const int swz = xcd_swz(blockIdx.x, gridDim.x);
  const int r   = swz % 52;
  const int b   = swz / 52;
  const int bx  = r & 3;
  const int mt  = r >> 2;
  const int tid = threadIdx.x, wid = tid >> 6, lane = tid & 63;
  const int wm = wid >> 2, wn = wid & 3;
  const int arow = lane & 15, col16 = lane >> 4;   // col16 in 0..3
  const int n00 = mt * 256, co00 = bx * 256;

  // staging: lane covers (row = base + (lane>>2), unit = lane&3); source unit inverse-swizzled
  const int srow = wid * 16 + (lane >> 2);
  const int tc   = ((lane & 3) ^ ((lane >> 3) & 3)) * 8;   // = (unit ^ ((row>>1)&3))*8 elems
  int na0 = n00 + srow;        if (na0 >= NN) na0 = NN - 1;
  int na1 = n00 + srow + 128;  if (na1 >= NN) na1 = NN - 1;
  const int y0 = na0 / WW, x0v = na0 % WW;
  const int y1 = na1 / WW, x1v = na1 % WW;
  const unsigned short* aS0 = xpad + ((int64_t)(b * HP + y0) * WP + x0v) * CDIM + tc;
  const unsigned short* aS1 = xpad + ((int64_t)(b * HP + y1) * WP + x1v) * CDIM + tc;
  const unsigned short* bS0 = Wb + (int64_t)(co00 + srow) * CDIM + tc;
  const unsigned short* bS1 = Wb + (int64_t)(co00 + srow + 128) * CDIM + tc;

  // ds_read swizzled unit offset (elems): row in a kk-half has 4 units of 16B
  const int rdsz = (col16 ^ ((arow >> 1) & 3)) * 8;

  f32x4 acc[8][4] = {};

#define STAGE_A(s, kk, aoffv)                                        \
  { unsigned short* d = lds + (s) * 32768 + (kk) * 8192 + wid * 512; \
    gload_lds16(aS0 + (aoffv) + (kk) * 32, d);                       \
    gload_lds16(aS1 + (aoffv) + (kk) * 32, d + 4096); }
#define STAGE_B(s, kk, boffv)                                                \
  { unsigned short* d = lds + (s) * 32768 + 16384 + (kk) * 8192 + wid * 512; \
    gload_lds16(bS0 + (boffv) + (kk) * 32, d);                               \
    gload_lds16(bS1 + (boffv) + (kk) * 32, d + 4096); }
#define KOFF(ks, aoffv, boffv)                              \
  { const int tap = (ks) >> 2;                              \
    const int dy = (tap >= 6) + (tap >= 3);                 \
    const int dx = tap - dy * 3;                            \
    const int cb = ((ks) & 3) << 6;                         \
    aoffv = (dy * WP + dx) * CDIM + cb;                     \
    boffv = tap * 262144 + cb; }

  // prologue: stage all 4 chunks of K-step 0 in phase order, then guard c1,c2.
  int aoff0, boff0;
  KOFF(0, aoff0, boff0);
  STAGE_A(0, 0, aoff0); STAGE_B(0, 0, boff0);
  STAGE_A(0, 1, aoff0); STAGE_B(0, 1, boff0);
  asm volatile("s_waitcnt vmcnt(4)" ::: "memory");
  __builtin_amdgcn_s_barrier();
  asm volatile("" ::: "memory");

#define MFMA_PAIR(n0i, n1i)                                                              \
  __builtin_amdgcn_s_setprio(1);                                                        \
  _Pragma("unroll")                                                                      \
  for (int mf = 0; mf < 8; ++mf) {                                                       \
    acc[mf][n0i] = __builtin_amdgcn_mfma_f32_16x16x32_bf16(av[mf], bv0, acc[mf][n0i], 0, 0, 0); \
    acc[mf][n1i] = __builtin_amdgcn_mfma_f32_16x16x32_bf16(av[mf], bv1, acc[mf][n1i], 0, 0, 0); \
  }                                                                                      \
  __builtin_amdgcn_s_setprio(0);
#define BAR_PRE()                                              \
  __builtin_amdgcn_s_barrier();                                \
  asm volatile("s_waitcnt lgkmcnt(0)" ::: "memory");           \
  __builtin_amdgcn_sched_barrier(0);
#define BAR_POST()                                             \
  asm volatile("" ::: "memory");                               \
  __builtin_amdgcn_s_barrier();                                \
  asm volatile("" ::: "memory");

  #pragma unroll 1
  for (int t = 0; t < 36; ++t) {
    const int cur = t & 1, nxt = cur ^ 1;
    const int tn = (t < 35) ? t + 1 : 35;
    int aoffn, boffn;
    KOFF(tn, aoffn, boffn);
    unsigned short* sA0 = lds + cur * 32768;
    unsigned short* sB0 = sA0 + 16384;
    bf16x8 av[8], bv0, bv1;

    // ---- P1: reads A-k0 (all mf) + B-k0 nf{0,1}; stage c1(t+1)=A-k0 ----
    #pragma unroll
    for (int mf = 0; mf < 8; ++mf)
      av[mf] = *(const bf16x8*)(sA0 + (wm * 128 + mf * 16 + arow) * 32 + rdsz);
    bv0 = *(const bf16x8*)(sB0 + (wn * 64 + 0 + arow) * 32 + rdsz);
    bv1 = *(const bf16x8*)(sB0 + (wn * 64 + 16 + arow) * 32 + rdsz);
    STAGE_A(nxt, 0, aoffn);
    BAR_PRE();
    MFMA_PAIR(0, 1);
    BAR_POST();

    // ---- P2: reads B-k0 nf{2,3}; stage c2(t+1)=B-k0; vmcnt guards c3,c4(t) ----
    bv0 = *(const bf16x8*)(sB0 + (wn * 64 + 32 + arow) * 32 + rdsz);
    bv1 = *(const bf16x8*)(sB0 + (wn * 64 + 48 + arow) * 32 + rdsz);
    STAGE_B(nxt, 0, boffn);
    asm volatile("s_waitcnt vmcnt(4)" ::: "memory");
    BAR_PRE();
    MFMA_PAIR(2, 3);
    BAR_POST();

    // ---- P3: reads A-k1 (all mf) + B-k1 nf{0,1}; stage c3(t+1)=A-k1 ----
    #pragma unroll
    for (int mf = 0; mf < 8; ++mf)
      av[mf] = *(const bf16x8*)(sA0 + 8192 + (wm * 128 + mf * 16 + arow) * 32 + rdsz);
    bv0 = *(const bf16x8*)(sB0 + 8192 + (wn * 64 + 0 + arow) * 32 + rdsz);
    bv1 = *(const bf16x8*)(sB0 + 8192 + (wn * 64 + 16 + arow) * 32 + rdsz);
    STAGE_A(nxt, 1, aoffn);
    BAR_PRE();
    MFMA_PAIR(0, 1);
    BAR_POST();

    // ---- P4: reads B-k1 nf{2,3}; stage c4(t+1)=B-k1; vmcnt guards c1,c2(t+1) ----
    bv0 = *(const bf16x8*)(sB0 + 8192 + (wn * 64 + 32 + arow) * 32 + rdsz);
    bv1 = *(const bf16x8*)(sB0 + 8192 + (wn * 64 + 48 + arow) * 32 + rdsz);
    STAGE_B(nxt, 1, boffn);
    asm volatile("s_waitcnt vmcnt(4)" ::: "memory");
    BAR_PRE();
    MFMA_PAIR(2, 3);
    BAR_POST();
  }

  asm volatile("s_waitcnt vmcnt(0)" ::: "memory");

  const int rowoff = col16 * 4;
  #pragma unroll
  for (int mf = 0; mf < 8; ++mf) {
    const int nr = n00 + wm * 128 + mf * 16 + rowoff;
    #pragma unroll
    for (int nf = 0; nf < 4; ++nf) {
      const int co = co00 + wn * 64 + nf * 16 + arow;
      const float bvs = bias[co];
      const float v0 = acc[mf][nf][0] + bvs;
      const float v1 = acc[mf][nf][1] + bvs;
      const float v2 = acc[mf][nf][2] + bvs;
      const float v3 = acc[mf][nf][3] + bvs;
      if (bx < 2) {
        const int h = co >> 6, c = co & 63;
        unsigned short* dst = fxT + ((int64_t)((b * NH + h) * 64 + c)) * NPAD + nr;
        if (nr + 3 < NN) {
          ushort4_t o; o.x = f2bf(v0); o.y = f2bf(v1); o.z = f2bf(v2); o.w = f2bf(v3);
          *(ushort4_t*)dst = o;
        } else {
          if (nr + 0 < NN) dst[0] = f2bf(v0);
          if (nr + 1 < NN) dst[1] = f2bf(v1);
          if (nr + 2 < NN) dst[2] = f2bf(v2);
          if (nr + 3 < NN) dst[3] = f2bf(v3);
        }
      } else {
        const int h = (co >> 6) & 7, d = co & 63;
        unsigned short* dst = xmid + ((int64_t)(b * NH + h) * NPAD + nr) * 64 + d;
        if (nr + 0 < NN) dst[0] = f2bf(v0);
        if (nr + 1 < NN) dst[64] = f2bf(v1);
        if (nr + 2 < NN) dst[128] = f2bf(v2);
        if (nr + 3 < NN) dst[192] = f2bf(v3);
      }
    }
  }
#undef STAGE_A
#undef STAGE_B
#undef KOFF
#undef MFMA_PAIR
#undef BAR_PRE
#undef BAR_POST
}

// ---------------- K3: logits MFMA + softmax + eigens; LDS-staged coalesced stores -------
__global__ void k_eig(const unsigned short* __restrict__ xmid,
                      const unsigned short* __restrict__ gwb,
                      const float* __restrict__ gateb,
                      const float* __restrict__ temperature,
                      const float* __restrict__ inver,
                      unsigned short* __restrict__ eigT,
                      unsigned short* __restrict__ eigN) {
  __shared__ unsigned short egN[64 * 72];
  __shared__ unsigned short egT[64 * 72];
  const int nt = blockIdx.x, h = blockIdx.y, b = blockIdx.z;
  const int tid = threadIdx.x;
  const int w = tid >> 6, lane = tid & 63;
  const int n0 = nt * 64 + w * 16;
  const int bh = b * NH + h;
  float tv = temperature[h];
  tv = fminf(fmaxf(tv, 0.1f), 5.0f);
  const float itemp = 1.0f / tv;
  const int arow = lane & 15;
  const int koff = (lane >> 4) * 8;
  const unsigned short* aptr = xmid + ((int64_t)bh * NPAD + (n0 + arow)) * 64 + koff;
  bf16x8 a0 = *(const bf16x8*)(aptr);
  bf16x8 a1 = *(const bf16x8*)(aptr + 32);
  f32x4 acc[4] = {};
  #pragma unroll
  for (int ng = 0; ng < 4; ++ng) {
    const unsigned short* bptr = gwb + (ng * 16 + arow) * 64 + koff;
    bf16x8 b0 = *(const bf16x8*)(bptr);
    bf16x8 b1 = *(const bf16x8*)(bptr + 32);
    acc[ng] = __builtin_amdgcn_mfma_f32_16x16x32_bf16(a0, b0, acc[ng], 0, 0, 0);
    acc[ng] = __builtin_amdgcn_mfma_f32_16x16x32_bf16(a1, b1, acc[ng], 0, 0, 0);
  }
  #pragma unroll
  for (int r = 0; r < 4; ++r) {
    const int nl = w * 16 + ((lane >> 4) << 2) + r;
    const int n = nt * 64 + nl;
    float vals[4];
    #pragma unroll
    for (int ng = 0; ng < 4; ++ng) vals[ng] = (acc[ng][r] + gateb[ng * 16 + arow]) * itemp;
    float mx = fmaxf(fmaxf(vals[0], vals[1]), fmaxf(vals[2], vals[3]));
    #pragma unroll
    for (int s = 1; s < 16; s <<= 1) mx = fmaxf(mx, __shfl_xor(mx, s));
    float ex[4]; float sum = 0.f;
    #pragma unroll
    for (int ng = 0; ng < 4; ++ng) { ex[ng] = __expf(vals[ng] - mx); sum += ex[ng]; }
    #pragma unroll
    for (int s = 1; s < 16; s <<= 1) sum += __shfl_xor(sum, s);
    const float inv = 1.0f / sum;
    const bool valid = (n < NN);
    #pragma unroll
    for (int ng = 0; ng < 4; ++ng) {
      const int g = ng * 16 + arow;
      float iv = valid ? inver[(int64_t)n * GG + g] : 0.f;
      unsigned short u = valid ? f2bf(ex[ng] * inv * iv) : (unsigned short)0;
      egN[nl * 72 + g] = u;
      egT[g * 72 + nl] = u;
    }
  }
  __syncthreads();
  const int row = tid >> 2, c0 = (tid & 3) << 4;
  {
    ushort8_t v0 = *(ushort8_t*)&egN[row * 72 + c0];
    ushort8_t v1 = *(ushort8_t*)&egN[row * 72 + c0 + 8];
    unsigned short* dst = eigN + ((int64_t)bh * NPAD + nt * 64 + row) * 64 + c0;
    *(ushort8_t*)dst = v0; *(ushort8_t*)(dst + 8) = v1;
  }
  {
    ushort8_t v0 = *(ushort8_t*)&egT[row * 72 + c0];
    ushort8_t v1 = *(ushort8_t*)&egT[row * 72 + c0 + 8];
    unsigned short* dst = eigT + ((int64_t)(bh * 64 + row)) * NPAD + nt * 64 + c0;
    *(ushort8_t*)dst = v0; *(ushort8_t*)(dst + 8) = v1;
  }
}

// ---------------- K4: fused spec-GEMM + LayerNorm + (LN(spec) @ P_h) -> m2t ------------
__launch_bounds__(256, 1)
__global__ void k_specln(const unsigned short* __restrict__ eigT,
                         const unsigned short* __restrict__ fxT,
                         const float* __restrict__ gamma, const float* __restrict__ beta,
                         const unsigned short* __restrict__ Pt,
                         unsigned short* __restrict__ m2t) {
  extern __shared__ char sm[];
  float* sacc = (float*)sm;                                   // [4][64][65] f32
  unsigned short* specb = (unsigned short*)(sm + 66560);      // [64][64] bf16 swz
  float* red = (float*)(sm + 74752);
  unsigned short* mstrip = (unsigned short*)(sm + 74784);     // [4][64][72] u16
  const int bhl = blockIdx.x;
  const int h = bhl & 7, bl = bhl >> 3;
  const int tid = threadIdx.x, w = tid >> 6, lane = tid & 63;
  const int arow = lane & 15, col16 = lane >> 4;
  const int koff = col16 * 8;
  const unsigned short* eb = eigT + (int64_t)bhl * 64 * NPAD;
  const unsigned short* fb = fxT + (int64_t)bhl * 64 * NPAD;

  const int ks0 = (98 * w) >> 2, ks1 = (98 * (w + 1)) >> 2;
  f32x4 acc[4][4] = {};
  for (int ks = ks0; ks < ks1; ++ks) {
    const int k0 = ks * 32 + koff;
    bf16x8 av[4], bv[4];
    #pragma unroll
    for (int mg = 0; mg < 4; ++mg) av[mg] = *(const bf16x8*)(eb + (int64_t)(mg * 16 + arow) * NPAD + k0);
    #pragma unroll
    for (int ng = 0; ng < 4; ++ng) bv[ng] = *(const bf16x8*)(fb + (int64_t)(ng * 16 + arow) * NPAD + k0);
    #pragma unroll
    for (int mg = 0; mg < 4; ++mg)
      #pragma unroll
      for (int ng = 0; ng < 4; ++ng)
        acc[mg][ng] = __builtin_amdgcn_mfma_f32_16x16x32_bf16(av[mg], bv[ng], acc[mg][ng], 0, 0, 0);
  }
  float* pw = sacc + w * (64 * 65);
  #pragma unroll
  for (int mg = 0; mg < 4; ++mg)
    #pragma unroll
    for (int ng = 0; ng < 4; ++ng)
      #pragma unroll
      for (int r = 0; r < 4; ++r)
        pw[(mg * 16 + col16 * 4 + r) * 65 + ng * 16 + arow] = acc[mg][ng][r];
  __syncthreads();

  float vloc[16];
  float lsum = 0.f, lsq = 0.f;
  #pragma unroll
  for (int idx = 0; idx < 16; ++idx) {
    const int e = tid + idx * 256;
    const int g = e >> 6, c = e & 63;
    float v = sacc[g * 65 + c] + sacc[4160 + g * 65 + c] +
              sacc[8320 + g * 65 + c] + sacc[12480 + g * 65 + c];
    vloc[idx] = v; lsum += v; lsq += v * v;
  }
  #pragma unroll
  for (int s = 1; s < 64; s <<= 1) { lsum += __shfl_xor(lsum, s); lsq += __shfl_xor(lsq, s); }
  if (lane == 0) { red[w] = lsum; red[4 + w] = lsq; }
  __syncthreads();
  const float tsum = red[0] + red[1] + red[2] + red[3];
  const float tsq = red[4] + red[5] + red[6] + red[7];
  const float mu = tsum * (1.0f / 4096.0f);
  const float var = tsq * (1.0f / 4096.0f) - mu * mu;
  const float rs = rsqrtf(var + 1e-5f);
  #pragma unroll
  for (int idx = 0; idx < 16; ++idx) {
    const int e = tid + idx * 256;
    const int g = e >> 6, c = e & 63;
    float sv = (vloc[idx] - mu) * rs * gamma[e] + beta[e];
    specb[g * 64 + ((((c >> 3) ^ (g & 7))) << 3) + (c & 7)] = f2bf(sv);
  }
  __syncthreads();

  f32x4 a2[4][4] = {};
  const unsigned short* pth = Pt + ((int64_t)h * 256 + w * 64) * 64;
  #pragma unroll
  for (int kk = 0; kk < 2; ++kk) {
    const int i0 = kk * 32 + koff;
    const int i8 = (i0 >> 3);
    bf16x8 av2[4], bv2[4];
    #pragma unroll
    for (int mg = 0; mg < 4; ++mg) {
      const int g = mg * 16 + arow;
      av2[mg] = *(const bf16x8*)(specb + g * 64 + ((i8 ^ (g & 7)) << 3));
    }
    #pragma unroll
    for (int ng = 0; ng < 4; ++ng)
      bv2[ng] = *(const bf16x8*)(pth + (ng * 16 + arow) * 64 + i0);
    #pragma unroll
    for (int mg = 0; mg < 4; ++mg)
      #pragma unroll
      for (int ng = 0; ng < 4; ++ng)
        a2[mg][ng] = __builtin_amdgcn_mfma_f32_16x16x32_bf16(av2[mg], bv2[ng], a2[mg][ng], 0, 0, 0);
  }
  unsigned short* ms = mstrip + w * (64 * 72);
  #pragma unroll
  for (int mg = 0; mg < 4; ++mg)
    #pragma unroll
    for (int ng = 0; ng < 4; ++ng)
      #pragma unroll
      for (int r = 0; r < 4; ++r)
        ms[(ng * 16 + arow) * 72 + mg * 16 + col16 * 4 + r] = f2bf(a2[mg][ng][r]);
  __syncthreads();
  #pragma unroll
  for (int e0 = 0; e0 < 8; ++e0) {
    const int e = lane + e0 * 64;
    const int row = e >> 3, g8 = e & 7;
    ushort8_t v = *(ushort8_t*)&ms[row * 72 + g8 * 8];
    *(ushort8_t*)(m2t + ((int64_t)(bl * 256 + w * 64 + row)) * 512 + h * 64 + g8 * 8) = v;
  }
}

// ---------------- K5: final out GEMM ----------------
__launch_bounds__(256)
__global__ void k_out(const unsigned short* __restrict__ eigN,
                      const unsigned short* __restrict__ m2t,
                      const float* __restrict__ outb,
                      float* __restrict__ out, int b0) {
  const int swz = xcd_swz(blockIdx.x, gridDim.x);
  const int ct = swz & 1;
  const int mt = (swz >> 1) % 25;
  const int b  = swz / 50;
  const int w = threadIdx.x >> 6, lane = threadIdx.x & 63;
  const int wm = w >> 1, wn = w & 1;
  const int arow = lane & 15, koff = (lane >> 4) * 8;
  const int co0 = ct * 128 + wn * 64;
  const int n0 = mt * 128 + wm * 64;
  f32x4 acc[4][4] = {};
  const unsigned short* ebase = eigN + (int64_t)b * NH * NPAD * 64;
  const unsigned short* mbase = m2t + (int64_t)b * 256 * 512;
  for (int ks = 0; ks < 16; ++ks) {
    const int hh = ks >> 1;
    const int g0 = (ks & 1) * 32 + koff;
    bf16x8 av[4], bv[4];
    #pragma unroll
    for (int mg = 0; mg < 4; ++mg) {
      int n = n0 + mg * 16 + arow;
      if (n > NPAD - 1) n = NPAD - 1;
      av[mg] = *(const bf16x8*)(ebase + ((int64_t)hh * NPAD + n) * 64 + g0);
    }
    #pragma unroll
    for (int ng = 0; ng < 4; ++ng)
      bv[ng] = *(const bf16x8*)(mbase + (int64_t)(co0 + ng * 16 + arow) * 512 + ks * 32 + koff);
    #pragma unroll
    for (int mg = 0; mg < 4; ++mg)
      #pragma unroll
      for (int ng = 0; ng < 4; ++ng)
        acc[mg][ng] = __builtin_amdgcn_mfma_f32_16x16x32_bf16(av[mg], bv[ng], acc[mg][ng], 0, 0, 0);
  }
  #pragma unroll
  for (int mg = 0; mg < 4; ++mg) {
    const int nr = n0 + mg * 16 + ((lane >> 4) << 2);
    #pragma unroll
    for (int ng = 0; ng < 4; ++ng) {
      const int co = co0 + ng * 16 + arow;
      const float bv = outb[co];
      #pragma unroll
      for (int r = 0; r < 4; ++r) {
        if (nr + r < NN)
          out[((int64_t)(b0 + b) * NN + nr + r) * 256 + co] = acc[mg][ng][r] + bv;
      }
    }
  }
}

extern "C" void kernel_launch(void* const* d_in, const int* in_sizes, int n_in,
                              void* d_out, int out_size, void* d_ws, size_t ws_size,
                              hipStream_t stream) {
  const float* x     = (const float*)d_in[0];
  const float* fxw   = (const float*)d_in[1];
  const float* fxb   = (const float*)d_in[2];
  const float* xw    = (const float*)d_in[3];
  const float* xb    = (const float*)d_in[4];
  const float* gw    = (const float*)d_in[5];
  const float* gb    = (const float*)d_in[6];
  const float* temp  = (const float*)d_in[7];
  const float* gamma = (const float*)d_in[8];
  const float* beta  = (const float*)d_in[9];
  const float* mlp   = (const float*)d_in[10];
  const float* outw  = (const float*)d_in[11];
  const float* outb  = (const float*)d_in[12];
  const float* inver = (const float*)d_in[13];
  float* out = (float*)d_out;
  char* ws = (char*)d_ws;
  (void)in_sizes; (void)n_in; (void)out_size;

  hipFuncSetAttribute(reinterpret_cast<const void*>(k_conv8),
                      hipFuncAttributeMaxDynamicSharedMemorySize, 131072);
  hipFuncSetAttribute(reinterpret_cast<const void*>(k_specln),
                      hipFuncAttributeMaxDynamicSharedMemorySize, 131072);

  int CB = 1;
  {
    const int cands[6] = {32, 16, 8, 4, 2, 1};
    for (int i = 0; i < 6; ++i) {
      unsigned long long need = 4993024ull + (unsigned long long)cands[i] * 14847488ull;
      if (need <= (unsigned long long)ws_size) { CB = cands[i]; break; }
    }
  }

  unsigned short* Wb   = (unsigned short*)(ws + 0);
  float*          bias = (float*)(ws + 4718592);
  unsigned short* gwb  = (unsigned short*)(ws + 4722688);
  unsigned short* Pt   = (unsigned short*)(ws + 4730880);
  const size_t F0      = 4993024;
  const size_t szXpad  = (size_t)CB * 1740288;
  const size_t szM2t   = (size_t)CB * 262144;
  const size_t szBig   = (size_t)CB * 3211264;
  unsigned short* xpad = (unsigned short*)(ws + F0);
  unsigned short* m2t  = (unsigned short*)(ws + F0 + szXpad);
  unsigned short* fxT  = (unsigned short*)(ws + F0 + szXpad + szM2t);
  unsigned short* xmid = (unsigned short*)(ws + F0 + szXpad + szM2t + szBig);
  unsigned short* eigT = (unsigned short*)(ws + F0 + szXpad + szM2t + 2 * szBig);
  unsigned short* eigN = (unsigned short*)(ws + F0 + szXpad + szM2t + 3 * szBig);

  k_wpack<<<dim3(9216), dim3(256), 0, stream>>>(fxw, xw, fxb, xb, gw, Wb, bias, gwb);
  k_pprep<<<dim3(512), dim3(256), 0, stream>>>(mlp, outw, Pt);

  for (int b0 = 0; b0 < BB; b0 += CB) {
    k_pad<<<dim3(WP, HP, CB), dim3(64), 0, stream>>>(x, xpad, b0);
    k_padzero<<<dim3(CB * 10), dim3(256), 0, stream>>>(fxT, xmid, CB);
    k_conv8<<<dim3(52 * CB), dim3(512), 131072, stream>>>(xpad, Wb, bias, fxT, xmid);
    k_eig<<<dim3(49, 8, CB), dim3(256), 0, stream>>>(xmid, gwb, gb, temp, inver, eigT, eigN);
    k_specln<<<dim3(CB * 8), dim3(256), 111648, stream>>>(eigT, fxT, gamma, beta, Pt, m2t);
    k_out<<<dim3(50 * CB), dim3(256), 0, stream>>>(eigN, m2t, outb, out, b0);
  }
}

// Round 7
// 884.932 us; speedup vs baseline: 1.4009x; 1.0233x over previous
//
#include <hip/hip_runtime.h>
#include <hip/hip_bf16.h>
#include <stdint.h>

#define HH 101
#define WW 31
#define NN 3131
#define NPAD 3136
#define BB 32
#define NH 8
#define CDIM 256
#define GG 64
#define HP 103
#define WP 33

typedef __attribute__((ext_vector_type(8))) short bf16x8;
typedef __attribute__((ext_vector_type(4))) float f32x4;
typedef __attribute__((ext_vector_type(4))) unsigned short ushort4_t;
typedef __attribute__((ext_vector_type(8))) unsigned short ushort8_t;
typedef __attribute__((ext_vector_type(4))) float float4_t;

static __device__ __forceinline__ unsigned short f2bf(float f) {
  union { float f; uint32_t u; } v; v.f = f;
  uint32_t u = v.u;
  return (unsigned short)((u + 0x7fffu + ((u >> 16) & 1u)) >> 16);
}
static __device__ __forceinline__ float bf2f(unsigned short h) {
  union { uint32_t u; float f; } v; v.u = ((uint32_t)h) << 16;
  return v.f;
}
static __device__ __forceinline__ void gload_lds16(const void* g, void* l) {
  __builtin_amdgcn_global_load_lds((const __attribute__((address_space(1))) void*)g,
                                   (__attribute__((address_space(3))) void*)l, 16, 0, 0);
}
// m204 bijective XCD swizzle
static __device__ __forceinline__ int xcd_swz(int bid, int nwg) {
  int q = nwg >> 3, r = nwg & 7;
  int xcd = bid & 7, pos = bid >> 3;
  int base = (xcd < r) ? xcd * (q + 1) : r * (q + 1) + (xcd - r) * q;
  return base + pos;
}

// ---------------- K0: pad + cast x -> bf16 (CB, HP, WP, C) ----------------
__global__ void k_pad(const float* __restrict__ x, unsigned short* __restrict__ xpad, int b0) {
  const int xx = blockIdx.x, yy = blockIdx.y, b = blockIdx.z;
  const int t = threadIdx.x;
  ushort4_t o; o.x = 0; o.y = 0; o.z = 0; o.w = 0;
  if (yy >= 1 && yy <= HH && xx >= 1 && xx <= WW) {
    const int n = (yy - 1) * WW + (xx - 1);
    const float4_t v = *(const float4_t*)(x + (((int64_t)(b0 + b) * NN + n) * CDIM + t * 4));
    o.x = f2bf(v.x); o.y = f2bf(v.y); o.z = f2bf(v.z); o.w = f2bf(v.w);
  }
  *(ushort4_t*)(xpad + (((int64_t)b * HP + yy) * WP + xx) * CDIM + t * 4) = o;
}

// ---------------- K1: pack conv weights, bias, gate_w ----------------
__global__ void k_wpack(const float* __restrict__ fxw, const float* __restrict__ xw,
                        const float* __restrict__ fxb, const float* __restrict__ xb,
                        const float* __restrict__ gw,
                        unsigned short* __restrict__ Wb, float* __restrict__ bias,
                        unsigned short* __restrict__ gwb) {
  int tid = blockIdx.x * blockDim.x + threadIdx.x;
  const int total = 9 * 1024 * 256;
  if (tid < total) {
    int cin = tid & 255; int rest = tid >> 8; int co = rest & 1023; int t = rest >> 10;
    float v = (co < 512) ? fxw[(int64_t)co * 2304 + cin * 9 + t]
                         : xw[(int64_t)(co - 512) * 2304 + cin * 9 + t];
    Wb[tid] = f2bf(v);
  }
  if (tid < 1024) bias[tid] = (tid < 512) ? fxb[tid] : xb[tid - 512];
  if (tid < 4096) gwb[tid] = f2bf(gw[tid]);
}

// ---------------- K1b: Pt[h][co][i] = sum_c mlp_w[i][c] * out_w[co][h*64+c] (bf16) --------
__global__ void k_pprep(const float* __restrict__ mlp, const float* __restrict__ outw,
                        unsigned short* __restrict__ Pt) {
  int h = blockIdx.x >> 6, i = blockIdx.x & 63, co = threadIdx.x;
  float a = 0.f;
  for (int c = 0; c < 64; ++c) a += mlp[i * 64 + c] * outw[(int64_t)co * 512 + h * 64 + c];
  Pt[((int64_t)h * 256 + co) * 64 + i] = f2bf(a);
}

// ---------------- K1c: zero pad tails of fxT (cols) and xmid (rows) ----------
__global__ void k_padzero(unsigned short* __restrict__ fxT, unsigned short* __restrict__ xmid,
                          int CB) {
  int tid = blockIdx.x * blockDim.x + threadIdx.x;
  if (tid >= CB * 2560) return;
  {
    int j = tid % 5; int rc = tid / 5;
    fxT[(int64_t)rc * NPAD + NN + j] = 0;
  }
  {
    int d = tid & 63; int rest = tid >> 6;
    int j = rest % 5; int bh = rest / 5;
    xmid[((int64_t)bh * NPAD + NN + j) * 64 + d] = 0;
  }
}

// ---------------- K2: 256x256 conv, register-pipelined 4-phase schedule -------------
// 8 waves as 4M x 2N, wave tile 64x128. BK=64, 2 LDS buffers (128KB).
// Each phase: issue NEXT phase's ds_reads + 1 stage chunk, counted lgkmcnt (4/8,
// never 0 mid-loop), then 16 MFMA -> LDS pipe streams under the matrix pipe.
// Two {vmcnt(4); s_barrier} sync points per K-step (chunk-forcing audited).
__launch_bounds__(512, 2)
__global__ void k_conv8(const unsigned short* __restrict__ xpad,
                        const unsigned short* __restrict__ Wb,
                        const float* __restrict__ bias,
                        unsigned short* __restrict__ fxT,
                        unsigned short* __restrict__ xmid) {
  extern __shared__ unsigned short lds[];   // 2 x 32768 elems
  const int swz = xcd_swz(blockIdx.x, gridDim.x);
  const int r   = swz % 52;
  const int b   = swz / 52;
  const int bx  = r & 3;
  const int mt  = r >> 2;
  const int tid = threadIdx.x, wid = tid >> 6, lane = tid & 63;
  const int wm = wid & 3, wn = wid >> 2;           // 4 M-waves x 2 N-waves
  const int arow = lane & 15, col16 = lane >> 4;
  const int n00 = mt * 256, co00 = bx * 256;

  // staging lane map (rows srow, srow+128; source 16B-unit inverse-swizzled)
  const int srow = wid * 16 + (lane >> 2);
  const int tc   = ((lane & 3) ^ ((lane >> 3) & 3)) * 8;
  int na0 = n00 + srow;        if (na0 >= NN) na0 = NN - 1;
  int na1 = n00 + srow + 128;  if (na1 >= NN) na1 = NN - 1;
  const int y0 = na0 / WW, x0v = na0 % WW;
  const int y1 = na1 / WW, x1v = na1 % WW;
  const unsigned short* aS0 = xpad + ((int64_t)(b * HP + y0) * WP + x0v) * CDIM + tc;
  const unsigned short* aS1 = xpad + ((int64_t)(b * HP + y1) * WP + x1v) * CDIM + tc;
  const unsigned short* bS0 = Wb + (int64_t)(co00 + srow) * CDIM + tc;
  const unsigned short* bS1 = Wb + (int64_t)(co00 + srow + 128) * CDIM + tc;

  const int rdsz = (col16 ^ ((arow >> 1) & 3)) * 8;

  f32x4 acc[4][8] = {};
  bf16x8 a0[4], a1[4], b03[4], b47[4];

#define STAGE_A(s, kk, aoffv)                                        \
  { unsigned short* d = lds + (s) * 32768 + (kk) * 8192 + wid * 512; \
    gload_lds16(aS0 + (aoffv) + (kk) * 32, d);                       \
    gload_lds16(aS1 + (aoffv) + (kk) * 32, d + 4096); }
#define STAGE_B(s, kk, boffv)                                                \
  { unsigned short* d = lds + (s) * 32768 + 16384 + (kk) * 8192 + wid * 512; \
    gload_lds16(bS0 + (boffv) + (kk) * 32, d);                               \
    gload_lds16(bS1 + (boffv) + (kk) * 32, d + 4096); }
#define KOFF(ks, aoffv, boffv)                              \
  { const int tap = (ks) >> 2;                              \
    const int dy = (tap >= 6) + (tap >= 3);                 \
    const int dx = tap - dy * 3;                            \
    const int cb = ((ks) & 3) << 6;                         \
    aoffv = (dy * WP + dx) * CDIM + cb;                     \
    boffv = tap * 262144 + cb; }
#define RD_A(dst, s, kk, mf)                                                             \
  dst = *(const bf16x8*)(lds + (s) * 32768 + (kk) * 8192 +                               \
                         (wm * 64 + (mf) * 16 + arow) * 32 + rdsz);
#define RD_B(dst, s, kk, nf)                                                             \
  dst = *(const bf16x8*)(lds + (s) * 32768 + 16384 + (kk) * 8192 +                       \
                         (wn * 128 + (nf) * 16 + arow) * 32 + rdsz);
#define MFMA16(aset, bset, nbase)                                                        \
  __builtin_amdgcn_s_setprio(1);                                                         \
  _Pragma("unroll")                                                                      \
  for (int mf = 0; mf < 4; ++mf) {                                                       \
    _Pragma("unroll")                                                                    \
    for (int nf = 0; nf < 4; ++nf)                                                       \
      acc[mf][(nbase) + nf] =                                                            \
        __builtin_amdgcn_mfma_f32_16x16x32_bf16(aset[mf], bset[nf], acc[mf][(nbase) + nf], 0, 0, 0); \
  }                                                                                      \
  __builtin_amdgcn_s_setprio(0);

  // ---- prologue: stage K-step 0 fully; force kk0 chunks; preload A0,B03 ----
  int aoff0, boff0;
  KOFF(0, aoff0, boff0);
  STAGE_A(0, 0, aoff0); STAGE_B(0, 0, boff0);
  STAGE_A(0, 1, aoff0); STAGE_B(0, 1, boff0);
  asm volatile("s_waitcnt vmcnt(4)" ::: "memory");
  __builtin_amdgcn_s_barrier();
  asm volatile("" ::: "memory");
  #pragma unroll
  for (int i = 0; i < 4; ++i) { RD_A(a0[i], 0, 0, i); }
  #pragma unroll
  for (int i = 0; i < 4; ++i) { RD_B(b03[i], 0, 0, i); }

  #pragma unroll 1
  for (int t = 0; t < 36; ++t) {
    const int cur = t & 1, nxt = cur ^ 1;
    const int tn = (t < 35) ? t + 1 : 35;   // tail re-stage: dup data, reads discarded
    int aoffn, boffn;
    KOFF(tn, aoffn, boffn);

    // ---- P1: MFMA(a0 x b03, kk0). Prefetch b47(kk0); stage A-k0(t+1). ----
    #pragma unroll
    for (int i = 0; i < 4; ++i) { RD_B(b47[i], cur, 0, 4 + i); }
    STAGE_A(nxt, 0, aoffn);
    asm volatile("s_waitcnt lgkmcnt(4)" ::: "memory");   // a0,b03 ready (allow b47)
    __builtin_amdgcn_sched_barrier(0);
    MFMA16(a0, b03, 0);

    // ---- P2: stage B-k0(t+1); force kk1 chunks of cur; reads a1,b03(kk1); MFMA(a0 x b47). ----
    STAGE_B(nxt, 0, boffn);
    asm volatile("s_waitcnt vmcnt(4)" ::: "memory");     // forces A-k1,B-k1 of cur
    __builtin_amdgcn_s_barrier();
    asm volatile("" ::: "memory");
    #pragma unroll
    for (int i = 0; i < 4; ++i) { RD_A(a1[i], cur, 1, i); }
    #pragma unroll
    for (int i = 0; i < 4; ++i) { RD_B(b03[i], cur, 1, i); }
    asm volatile("s_waitcnt lgkmcnt(8)" ::: "memory");   // b47 ready (allow a1,b03)
    __builtin_amdgcn_sched_barrier(0);
    MFMA16(a0, b47, 4);

    // ---- P3: MFMA(a1 x b03, kk1). Prefetch b47(kk1); stage A-k1(t+1). ----
    #pragma unroll
    for (int i = 0; i < 4; ++i) { RD_B(b47[i], cur, 1, 4 + i); }
    STAGE_A(nxt, 1, aoffn);
    asm volatile("s_waitcnt lgkmcnt(4)" ::: "memory");   // a1,b03 ready (allow b47)
    __builtin_amdgcn_sched_barrier(0);
    MFMA16(a1, b03, 0);

    // ---- P4: stage B-k1(t+1); force kk0 chunks of nxt; reads a0,b03(kk0,nxt); MFMA(a1 x b47). ----
    STAGE_B(nxt, 1, boffn);
    asm volatile("s_waitcnt vmcnt(4)" ::: "memory");     // forces A-k0,B-k0 of nxt
    __builtin_amdgcn_s_barrier();
    asm volatile("" ::: "memory");
    #pragma unroll
    for (int i = 0; i < 4; ++i) { RD_A(a0[i], nxt, 0, i); }
    #pragma unroll
    for (int i = 0; i < 4; ++i) { RD_B(b03[i], nxt, 0, i); }
    asm volatile("s_waitcnt lgkmcnt(8)" ::: "memory");   // b47 ready (allow a0,b03)
    __builtin_amdgcn_sched_barrier(0);
    MFMA16(a1, b47, 4);
  }

  asm volatile("s_waitcnt vmcnt(0) lgkmcnt(0)" ::: "memory");

  const int rowoff = col16 * 4;
  #pragma unroll
  for (int mf = 0; mf < 4; ++mf) {
    const int nr = n00 + wm * 64 + mf * 16 + rowoff;
    #pragma unroll
    for (int nf = 0; nf < 8; ++nf) {
      const int co = co00 + wn * 128 + nf * 16 + arow;
      const float bvs = bias[co];
      const float v0 = acc[mf][nf][0] + bvs;
      const float v1 = acc[mf][nf][1] + bvs;
      const float v2 = acc[mf][nf][2] + bvs;
      const float v3 = acc[mf][nf][3] + bvs;
      if (bx < 2) {
        const int h = co >> 6, c = co & 63;
        unsigned short* dst = fxT + ((int64_t)((b * NH + h) * 64 + c)) * NPAD + nr;
        if (nr + 3 < NN) {
          ushort4_t o; o.x = f2bf(v0); o.y = f2bf(v1); o.z = f2bf(v2); o.w = f2bf(v3);
          *(ushort4_t*)dst = o;
        } else {
          if (nr + 0 < NN) dst[0] = f2bf(v0);
          if (nr + 1 < NN) dst[1] = f2bf(v1);
          if (nr + 2 < NN) dst[2] = f2bf(v2);
          if (nr + 3 < NN) dst[3] = f2bf(v3);
        }
      } else {
        const int h = (co >> 6) & 7, d = co & 63;
        unsigned short* dst = xmid + ((int64_t)(b * NH + h) * NPAD + nr) * 64 + d;
        if (nr + 0 < NN) dst[0] = f2bf(v0);
        if (nr + 1 < NN) dst[64] = f2bf(v1);
        if (nr + 2 < NN) dst[128] = f2bf(v2);
        if (nr + 3 < NN) dst[192] = f2bf(v3);
      }
    }
  }
#undef STAGE_A
#undef STAGE_B
#undef KOFF
#undef RD_A
#undef RD_B
#undef MFMA16
}

// ---------------- K3: logits MFMA + softmax + eigens; LDS-staged coalesced stores -------
__global__ void k_eig(const unsigned short* __restrict__ xmid,
                      const unsigned short* __restrict__ gwb,
                      const float* __restrict__ gateb,
                      const float* __restrict__ temperature,
                      const float* __restrict__ inver,
                      unsigned short* __restrict__ eigT,
                      unsigned short* __restrict__ eigN) {
  __shared__ unsigned short egN[64 * 72];
  __shared__ unsigned short egT[64 * 72];
  const int nt = blockIdx.x, h = blockIdx.y, b = blockIdx.z;
  const int tid = threadIdx.x;
  const int w = tid >> 6, lane = tid & 63;
  const int n0 = nt * 64 + w * 16;
  const int bh = b * NH + h;
  float tv = temperature[h];
  tv = fminf(fmaxf(tv, 0.1f), 5.0f);
  const float itemp = 1.0f / tv;
  const int arow = lane & 15;
  const int koff = (lane >> 4) * 8;
  const unsigned short* aptr = xmid + ((int64_t)bh * NPAD + (n0 + arow)) * 64 + koff;
  bf16x8 a0 = *(const bf16x8*)(aptr);
  bf16x8 a1 = *(const bf16x8*)(aptr + 32);
  f32x4 acc[4] = {};
  #pragma unroll
  for (int ng = 0; ng < 4; ++ng) {
    const unsigned short* bptr = gwb + (ng * 16 + arow) * 64 + koff;
    bf16x8 b0 = *(const bf16x8*)(bptr);
    bf16x8 b1 = *(const bf16x8*)(bptr + 32);
    acc[ng] = __builtin_amdgcn_mfma_f32_16x16x32_bf16(a0, b0, acc[ng], 0, 0, 0);
    acc[ng] = __builtin_amdgcn_mfma_f32_16x16x32_bf16(a1, b1, acc[ng], 0, 0, 0);
  }
  #pragma unroll
  for (int r = 0; r < 4; ++r) {
    const int nl = w * 16 + ((lane >> 4) << 2) + r;
    const int n = nt * 64 + nl;
    float vals[4];
    #pragma unroll
    for (int ng = 0; ng < 4; ++ng) vals[ng] = (acc[ng][r] + gateb[ng * 16 + arow]) * itemp;
    float mx = fmaxf(fmaxf(vals[0], vals[1]), fmaxf(vals[2], vals[3]));
    #pragma unroll
    for (int s = 1; s < 16; s <<= 1) mx = fmaxf(mx, __shfl_xor(mx, s));
    float ex[4]; float sum = 0.f;
    #pragma unroll
    for (int ng = 0; ng < 4; ++ng) { ex[ng] = __expf(vals[ng] - mx); sum += ex[ng]; }
    #pragma unroll
    for (int s = 1; s < 16; s <<= 1) sum += __shfl_xor(sum, s);
    const float inv = 1.0f / sum;
    const bool valid = (n < NN);
    #pragma unroll
    for (int ng = 0; ng < 4; ++ng) {
      const int g = ng * 16 + arow;
      float iv = valid ? inver[(int64_t)n * GG + g] : 0.f;
      unsigned short u = valid ? f2bf(ex[ng] * inv * iv) : (unsigned short)0;
      egN[nl * 72 + g] = u;
      egT[g * 72 + nl] = u;
    }
  }
  __syncthreads();
  const int row = tid >> 2, c0 = (tid & 3) << 4;
  {
    ushort8_t v0 = *(ushort8_t*)&egN[row * 72 + c0];
    ushort8_t v1 = *(ushort8_t*)&egN[row * 72 + c0 + 8];
    unsigned short* dst = eigN + ((int64_t)bh * NPAD + nt * 64 + row) * 64 + c0;
    *(ushort8_t*)dst = v0; *(ushort8_t*)(dst + 8) = v1;
  }
  {
    ushort8_t v0 = *(ushort8_t*)&egT[row * 72 + c0];
    ushort8_t v1 = *(ushort8_t*)&egT[row * 72 + c0 + 8];
    unsigned short* dst = eigT + ((int64_t)(bh * 64 + row)) * NPAD + nt * 64 + c0;
    *(ushort8_t*)dst = v0; *(ushort8_t*)(dst + 8) = v1;
  }
}

// ---------------- K4: fused spec-GEMM + LayerNorm + (LN(spec) @ P_h) -> m2t ------------
__launch_bounds__(256, 1)
__global__ void k_specln(const unsigned short* __restrict__ eigT,
                         const unsigned short* __restrict__ fxT,
                         const float* __restrict__ gamma, const float* __restrict__ beta,
                         const unsigned short* __restrict__ Pt,
                         unsigned short* __restrict__ m2t) {
  extern __shared__ char sm[];
  float* sacc = (float*)sm;                                   // [4][64][65] f32
  unsigned short* specb = (unsigned short*)(sm + 66560);      // [64][64] bf16 swz
  float* red = (float*)(sm + 74752);
  unsigned short* mstrip = (unsigned short*)(sm + 74784);     // [4][64][72] u16
  const int bhl = blockIdx.x;
  const int h = bhl & 7, bl = bhl >> 3;
  const int tid = threadIdx.x, w = tid >> 6, lane = tid & 63;
  const int arow = lane & 15, col16 = lane >> 4;
  const int koff = col16 * 8;
  const unsigned short* eb = eigT + (int64_t)bhl * 64 * NPAD;
  const unsigned short* fb = fxT + (int64_t)bhl * 64 * NPAD;

  const int ks0 = (98 * w) >> 2, ks1 = (98 * (w + 1)) >> 2;
  f32x4 acc[4][4] = {};
  for (int ks = ks0; ks < ks1; ++ks) {
    const int k0 = ks * 32 + koff;
    bf16x8 av[4], bv[4];
    #pragma unroll
    for (int mg = 0; mg < 4; ++mg) av[mg] = *(const bf16x8*)(eb + (int64_t)(mg * 16 + arow) * NPAD + k0);
    #pragma unroll
    for (int ng = 0; ng < 4; ++ng) bv[ng] = *(const bf16x8*)(fb + (int64_t)(ng * 16 + arow) * NPAD + k0);
    #pragma unroll
    for (int mg = 0; mg < 4; ++mg)
      #pragma unroll
      for (int ng = 0; ng < 4; ++ng)
        acc[mg][ng] = __builtin_amdgcn_mfma_f32_16x16x32_bf16(av[mg], bv[ng], acc[mg][ng], 0, 0, 0);
  }
  float* pw = sacc + w * (64 * 65);
  #pragma unroll
  for (int mg = 0; mg < 4; ++mg)
    #pragma unroll
    for (int ng = 0; ng < 4; ++ng)
      #pragma unroll
      for (int r = 0; r < 4; ++r)
        pw[(mg * 16 + col16 * 4 + r) * 65 + ng * 16 + arow] = acc[mg][ng][r];
  __syncthreads();

  float vloc[16];
  float lsum = 0.f, lsq = 0.f;
  #pragma unroll
  for (int idx = 0; idx < 16; ++idx) {
    const int e = tid + idx * 256;
    const int g = e >> 6, c = e & 63;
    float v = sacc[g * 65 + c] + sacc[4160 + g * 65 + c] +
              sacc[8320 + g * 65 + c] + sacc[12480 + g * 65 + c];
    vloc[idx] = v; lsum += v; lsq += v * v;
  }
  #pragma unroll
  for (int s = 1; s < 64; s <<= 1) { lsum += __shfl_xor(lsum, s); lsq += __shfl_xor(lsq, s); }
  if (lane == 0) { red[w] = lsum; red[4 + w] = lsq; }
  __syncthreads();
  const float tsum = red[0] + red[1] + red[2] + red[3];
  const float tsq = red[4] + red[5] + red[6] + red[7];
  const float mu = tsum * (1.0f / 4096.0f);
  const float var = tsq * (1.0f / 4096.0f) - mu * mu;
  const float rs = rsqrtf(var + 1e-5f);
  #pragma unroll
  for (int idx = 0; idx < 16; ++idx) {
    const int e = tid + idx * 256;
    const int g = e >> 6, c = e & 63;
    float sv = (vloc[idx] - mu) * rs * gamma[e] + beta[e];
    specb[g * 64 + ((((c >> 3) ^ (g & 7))) << 3) + (c & 7)] = f2bf(sv);
  }
  __syncthreads();

  f32x4 a2[4][4] = {};
  const unsigned short* pth = Pt + ((int64_t)h * 256 + w * 64) * 64;
  #pragma unroll
  for (int kk = 0; kk < 2; ++kk) {
    const int i0 = kk * 32 + koff;
    const int i8 = (i0 >> 3);
    bf16x8 av2[4], bv2[4];
    #pragma unroll
    for (int mg = 0; mg < 4; ++mg) {
      const int g = mg * 16 + arow;
      av2[mg] = *(const bf16x8*)(specb + g * 64 + ((i8 ^ (g & 7)) << 3));
    }
    #pragma unroll
    for (int ng = 0; ng < 4; ++ng)
      bv2[ng] = *(const bf16x8*)(pth + (ng * 16 + arow) * 64 + i0);
    #pragma unroll
    for (int mg = 0; mg < 4; ++mg)
      #pragma unroll
      for (int ng = 0; ng < 4; ++ng)
        a2[mg][ng] = __builtin_amdgcn_mfma_f32_16x16x32_bf16(av2[mg], bv2[ng], a2[mg][ng], 0, 0, 0);
  }
  unsigned short* ms = mstrip + w * (64 * 72);
  #pragma unroll
  for (int mg = 0; mg < 4; ++mg)
    #pragma unroll
    for (int ng = 0; ng < 4; ++ng)
      #pragma unroll
      for (int r = 0; r < 4; ++r)
        ms[(ng * 16 + arow) * 72 + mg * 16 + col16 * 4 + r] = f2bf(a2[mg][ng][r]);
  __syncthreads();
  #pragma unroll
  for (int e0 = 0; e0 < 8; ++e0) {
    const int e = lane + e0 * 64;
    const int row = e >> 3, g8 = e & 7;
    ushort8_t v = *(ushort8_t*)&ms[row * 72 + g8 * 8];
    *(ushort8_t*)(m2t + ((int64_t)(bl * 256 + w * 64 + row)) * 512 + h * 64 + g8 * 8) = v;
  }
}

// ---------------- K5: final out GEMM ----------------
__launch_bounds__(256)
__global__ void k_out(const unsigned short* __restrict__ eigN,
                      const unsigned short* __restrict__ m2t,
                      const float* __restrict__ outb,
                      float* __restrict__ out, int b0) {
  const int swz = xcd_swz(blockIdx.x, gridDim.x);
  const int ct = swz & 1;
  const int mt = (swz >> 1) % 25;
  const int b  = swz / 50;
  const int w = threadIdx.x >> 6, lane = threadIdx.x & 63;
  const int wm = w >> 1, wn = w & 1;
  const int arow = lane & 15, koff = (lane >> 4) * 8;
  const int co0 = ct * 128 + wn * 64;
  const int n0 = mt * 128 + wm * 64;
  f32x4 acc[4][4] = {};
  const unsigned short* ebase = eigN + (int64_t)b * NH * NPAD * 64;
  const unsigned short* mbase = m2t + (int64_t)b * 256 * 512;
  for (int ks = 0; ks < 16; ++ks) {
    const int hh = ks >> 1;
    const int g0 = (ks & 1) * 32 + koff;
    bf16x8 av[4], bv[4];
    #pragma unroll
    for (int mg = 0; mg < 4; ++mg) {
      int n = n0 + mg * 16 + arow;
      if (n > NPAD - 1) n = NPAD - 1;
      av[mg] = *(const bf16x8*)(ebase + ((int64_t)hh * NPAD + n) * 64 + g0);
    }
    #pragma unroll
    for (int ng = 0; ng < 4; ++ng)
      bv[ng] = *(const bf16x8*)(mbase + (int64_t)(co0 + ng * 16 + arow) * 512 + ks * 32 + koff);
    #pragma unroll
    for (int mg = 0; mg < 4; ++mg)
      #pragma unroll
      for (int ng = 0; ng < 4; ++ng)
        acc[mg][ng] = __builtin_amdgcn_mfma_f32_16x16x32_bf16(av[mg], bv[ng], acc[mg][ng], 0, 0, 0);
  }
  #pragma unroll
  for (int mg = 0; mg < 4; ++mg) {
    const int nr = n0 + mg * 16 + ((lane >> 4) << 2);
    #pragma unroll
    for (int ng = 0; ng < 4; ++ng) {
      const int co = co0 + ng * 16 + arow;
      const float bv = outb[co];
      #pragma unroll
      for (int r = 0; r < 4; ++r) {
        if (nr + r < NN)
          out[((int64_t)(b0 + b) * NN + nr + r) * 256 + co] = acc[mg][ng][r] + bv;
      }
    }
  }
}

extern "C" void kernel_launch(void* const* d_in, const int* in_sizes, int n_in,
                              void* d_out, int out_size, void* d_ws, size_t ws_size,
                              hipStream_t stream) {
  const float* x     = (const float*)d_in[0];
  const float* fxw   = (const float*)d_in[1];
  const float* fxb   = (const float*)d_in[2];
  const float* xw    = (const float*)d_in[3];
  const float* xb    = (const float*)d_in[4];
  const float* gw    = (const float*)d_in[5];
  const float* gb    = (const float*)d_in[6];
  const float* temp  = (const float*)d_in[7];
  const float* gamma = (const float*)d_in[8];
  const float* beta  = (const float*)d_in[9];
  const float* mlp   = (const float*)d_in[10];
  const float* outw  = (const float*)d_in[11];
  const float* outb  = (const float*)d_in[12];
  const float* inver = (const float*)d_in[13];
  float* out = (float*)d_out;
  char* ws = (char*)d_ws;
  (void)in_sizes; (void)n_in; (void)out_size;

  hipFuncSetAttribute(reinterpret_cast<const void*>(k_conv8),
                      hipFuncAttributeMaxDynamicSharedMemorySize, 131072);
  hipFuncSetAttribute(reinterpret_cast<const void*>(k_specln),
                      hipFuncAttributeMaxDynamicSharedMemorySize, 131072);

  int CB = 1;
  {
    const int cands[6] = {32, 16, 8, 4, 2, 1};
    for (int i = 0; i < 6; ++i) {
      unsigned long long need = 4993024ull + (unsigned long long)cands[i] * 14847488ull;
      if (need <= (unsigned long long)ws_size) { CB = cands[i]; break; }
    }
  }

  unsigned short* Wb   = (unsigned short*)(ws + 0);
  float*          bias = (float*)(ws + 4718592);
  unsigned short* gwb  = (unsigned short*)(ws + 4722688);
  unsigned short* Pt   = (unsigned short*)(ws + 4730880);
  const size_t F0      = 4993024;
  const size_t szXpad  = (size_t)CB * 1740288;
  const size_t szM2t   = (size_t)CB * 262144;
  const size_t szBig   = (size_t)CB * 3211264;
  unsigned short* xpad = (unsigned short*)(ws + F0);
  unsigned short* m2t  = (unsigned short*)(ws + F0 + szXpad);
  unsigned short* fxT  = (unsigned short*)(ws + F0 + szXpad + szM2t);
  unsigned short* xmid = (unsigned short*)(ws + F0 + szXpad + szM2t + szBig);
  unsigned short* eigT = (unsigned short*)(ws + F0 + szXpad + szM2t + 2 * szBig);
  unsigned short* eigN = (unsigned short*)(ws + F0 + szXpad + szM2t + 3 * szBig);

  k_wpack<<<dim3(9216), dim3(256), 0, stream>>>(fxw, xw, fxb, xb, gw, Wb, bias, gwb);
  k_pprep<<<dim3(512), dim3(256), 0, stream>>>(mlp, outw, Pt);

  for (int b0 = 0; b0 < BB; b0 += CB) {
    k_pad<<<dim3(WP, HP, CB), dim3(64), 0, stream>>>(x, xpad, b0);
    k_padzero<<<dim3(CB * 10), dim3(256), 0, stream>>>(fxT, xmid, CB);
    k_conv8<<<dim3(52 * CB), dim3(512), 131072, stream>>>(xpad, Wb, bias, fxT, xmid);
    k_eig<<<dim3(49, 8, CB), dim3(256), 0, stream>>>(xmid, gwb, gb, temp, inver, eigT, eigN);
    k_specln<<<dim3(CB * 8), dim3(256), 111648, stream>>>(eigT, fxT, gamma, beta, Pt, m2t);
    k_out<<<dim3(50 * CB), dim3(256), 0, stream>>>(eigN, m2t, outb, out, b0);
  }
}